// Round 5
// baseline (24950.775 us; speedup 1.0000x reference)
//
#include <hip/hip_runtime.h>
#include <cstdint>
#include <cstddef>

#define Bc 8
#define Lc 2048
#define Dc 1152
#define STRIDE 2080
#define G 8

// ---- K1 GEMM geometry ----
#define T_BLK 128            // positions per block
#define KT 32                // K-tile (8 chunks of 4 floats)
#define NKS (Dc / KT)        // 36
#define NCHUNK 9             // e-chunks (grid.y); 128 e's each
#define ECH 128
#define HS_NU (129 * 8)      // 16B units for H tile
#define W_NU (128 * 8)       // 16B units per W tile
#define QS_F 4128            // float offsets in LDS
#define KS_F 8224
#define LDS_F 12320          // 49280 B

__device__ __forceinline__ void gld16(const float* g, float* l) {
    __builtin_amdgcn_global_load_lds(
        (const __attribute__((address_space(1))) void*)(g),
        (__attribute__((address_space(3))) void*)(l), 16, 0, 0);
}

#define DOT4(a, b) ((a).x*(b).x + (a).y*(b).y + (a).z*(b).z + (a).w*(b).w)

// ---------------- Kernel 1: tiled fp32 dual-GEMM + fused cos-stats ----------------
// Shared-row trick: LDS row rho (= global t0-1+rho) feeds BOTH A_rho = Wq.h (q[t0+rho])
// and B_rho = Wk.h (k[t0+rho-1]). Thread (tx,ty): rows 8ty..8ty+8, e-cols tx+16j
// (j=0..7). Position t0+8ty+j: qq=|A_j|^2, kk=|B_{j+1}|^2, qk=A_j.B_{j+1} - all
// thread-local. Swizzles: H slot g^(rho>>3) (uniform per thread -> one base reg +
// immediate offsets), W slot g^(e&7) with e&7==tx&7 (one base reg + immediate
// offsets; Ks at +16384B). Stats folded once AFTER the K-loop (NEIT=1), so the
// K-loop's live set is just the 128 acc VGPRs + fragments.
__global__ __launch_bounds__(256, 2) void k1_gemm(
    const float* __restrict__ H, const float* __restrict__ Wq,
    const float* __restrict__ Wk, float* __restrict__ partial)
{
    __shared__ __align__(16) float Lds[LDS_F];
    float* Hs = Lds;
    float* Qs = Lds + QS_F;

    const int tid = threadIdx.x;
    const int bx = blockIdx.x;          // batch*16 + tile
    const int chunk = blockIdx.y;       // 0..8
    const int batch = bx >> 4;
    const int tile = bx & 15;
    const int t0 = 1 + tile * T_BLK;
    const float* Hb = H + (size_t)batch * Lc * Dc;
    const int eb = chunk * ECH;

    const int tx = tid & 15;
    const int ty = tid >> 4;

    float4 Aa[8], Ab[8], Ba[8], Bb[8];
    #pragma unroll
    for (int i = 0; i < 8; ++i) {
        Aa[i] = float4{0,0,0,0}; Ab[i] = float4{0,0,0,0};
        Ba[i] = float4{0,0,0,0}; Bb[i] = float4{0,0,0,0};
    }

    for (int ks = 0; ks < NKS; ++ks) {
        const int kb = ks * KT;
        // stage H window: unit u = rho*8+sl holds k-chunk (sl ^ (rho>>3))&7
        for (int u = tid; u < HS_NU; u += 256) {
            int rho = u >> 3;
            int srck = kb + ((((u & 7) ^ (rho >> 3)) & 7) << 2);
            int grow = t0 - 1 + rho; if (grow > Lc - 1) grow = Lc - 1;
            gld16(Hb + (size_t)grow * Dc + srck, Hs + u * 4);
        }
        // stage Wq/Wk tiles: unit u = er*8+sl holds k-chunk (sl ^ (er&7))
        for (int u = tid; u < W_NU; u += 256) {
            int er = u >> 3;
            int srck = kb + ((((u & 7) ^ er) & 7) << 2);
            size_t off = (size_t)(eb + er) * Dc + srck;
            gld16(Wq + off, Qs + u * 4);
            gld16(Wk + off, Qs + 4096 + u * 4);
        }
        __syncthreads();   // drains vmcnt before s_barrier

        #pragma unroll
        for (int g = 0; g < 8; ++g) {
            const float* hb  = Hs + ty * 256 + (((g ^ ty) & 7) << 2);
            const float* hb8 = Hs + ty * 256 + 256 + (((g ^ (ty + 1)) & 7) << 2);
            const float* wb  = Qs + tx * 32 + (((g ^ (tx & 7)) & 7) << 2);
            float4 h[9];
            #pragma unroll
            for (int i = 0; i < 8; ++i) h[i] = *(const float4*)(hb + i * 32);
            h[8] = *(const float4*)(hb8);
            // cols j=0..3 (e = tx+16j -> +512j floats; Wk at +4096 floats)
            {
                float4 q0 = *(const float4*)(wb);
                float4 q1 = *(const float4*)(wb + 512);
                float4 q2 = *(const float4*)(wb + 1024);
                float4 q3 = *(const float4*)(wb + 1536);
                float4 k0 = *(const float4*)(wb + 4096);
                float4 k1 = *(const float4*)(wb + 4608);
                float4 k2 = *(const float4*)(wb + 5120);
                float4 k3 = *(const float4*)(wb + 5632);
                #pragma unroll
                for (int i = 0; i < 8; ++i) {
                    Aa[i].x += DOT4(h[i], q0); Aa[i].y += DOT4(h[i], q1);
                    Aa[i].z += DOT4(h[i], q2); Aa[i].w += DOT4(h[i], q3);
                    Ba[i].x += DOT4(h[i+1], k0); Ba[i].y += DOT4(h[i+1], k1);
                    Ba[i].z += DOT4(h[i+1], k2); Ba[i].w += DOT4(h[i+1], k3);
                }
            }
            // cols j=4..7
            {
                float4 q0 = *(const float4*)(wb + 2048);
                float4 q1 = *(const float4*)(wb + 2560);
                float4 q2 = *(const float4*)(wb + 3072);
                float4 q3 = *(const float4*)(wb + 3584);
                float4 k0 = *(const float4*)(wb + 6144);
                float4 k1 = *(const float4*)(wb + 6656);
                float4 k2 = *(const float4*)(wb + 7168);
                float4 k3 = *(const float4*)(wb + 7680);
                #pragma unroll
                for (int i = 0; i < 8; ++i) {
                    Ab[i].x += DOT4(h[i], q0); Ab[i].y += DOT4(h[i], q1);
                    Ab[i].z += DOT4(h[i], q2); Ab[i].w += DOT4(h[i], q3);
                    Bb[i].x += DOT4(h[i+1], k0); Bb[i].y += DOT4(h[i+1], k1);
                    Bb[i].z += DOT4(h[i+1], k2); Bb[i].w += DOT4(h[i+1], k3);
                }
            }
        }
        __syncthreads();
    }

    // fused stats over this block's 128 e's, then reduce across the 16 tx-lanes
    float qq[8], kk[8], qk[8];
    #pragma unroll
    for (int j = 0; j < 8; ++j) {
        qq[j] = DOT4(Aa[j], Aa[j]) + DOT4(Ab[j], Ab[j]);
        kk[j] = DOT4(Ba[j], Ba[j]) + DOT4(Bb[j], Bb[j]);
        qk[j] = DOT4(Aa[j], Ba[j]) + DOT4(Ab[j], Bb[j]);
    }
    #pragma unroll
    for (int j = 0; j < 8; ++j) {
        #pragma unroll
        for (int off = 1; off <= 8; off <<= 1) {
            qq[j] += __shfl_xor(qq[j], off, 64);
            kk[j] += __shfl_xor(kk[j], off, 64);
            qk[j] += __shfl_xor(qk[j], off, 64);
        }
    }
    if (tx == 0) {
        #pragma unroll
        for (int j = 0; j < 8; ++j) {
            int t = t0 + 8 * ty + j;
            if (t < Lc) {
                size_t idx = (((size_t)chunk * Bc + batch) * Lc + t) * 3;
                partial[idx + 0] = qq[j];
                partial[idx + 1] = kk[j];
                partial[idx + 2] = qk[j];
            }
        }
    }
}

// ---------------- Kernel 1b: deterministic chunk-reduce -> bl ----------------
__global__ __launch_bounds__(256) void k1b_reduce(
    const float* __restrict__ partial, const float* __restrict__ ltemp,
    const float* __restrict__ bbias, float* __restrict__ bl_out)
{
    int idx = blockIdx.x * 256 + threadIdx.x;   // batch*Lc + t
    if (idx >= Bc * Lc) return;
    int t = idx & (Lc - 1);
    if (t == 0) return;
    float qq = 0.f, kk = 0.f, qk = 0.f;
    #pragma unroll
    for (int c = 0; c < NCHUNK; ++c) {
        size_t p = ((size_t)c * Bc * Lc + idx) * 3;
        qq += partial[p];
        kk += partial[p + 1];
        qk += partial[p + 2];
    }
    float T = expf(ltemp[0]);
    T = fminf(fmaxf(T, 0.1f), 10.0f);
    float den = fmaxf(sqrtf(qq), 1e-12f) * fmaxf(sqrtf(kk), 1e-12f);
    bl_out[idx] = (1.0f - qk / den) * T + bbias[0];
}

// ---------------- Kernel 2: boundary decision + stable compaction ----------------
__global__ __launch_bounds__(256) void k2_boundary(
    const float* __restrict__ bl_in, const int* __restrict__ mask,
    float* __restrict__ pv, int* __restrict__ bpos, int* __restrict__ nb)
{
    int b = blockIdx.x;
    int tid = threadIdx.x;
    const float* blb = bl_in + b * Lc;
    const int* mb = mask + b * Lc;

    float blv[8]; int f[8];
    int t0 = tid * 8;
    int s = 0;
    #pragma unroll
    for (int i = 0; i < 8; ++i) {
        int t = t0 + i;
        float v = (t == 0) ? 10.0f : blb[t];
        blv[i] = v;
        f[i] = (v > 0.0f && mb[t] != 0) ? 1 : 0;
        s += f[i];
    }
    int lane = tid & 63, wv = tid >> 6;
    int sc = s;
    #pragma unroll
    for (int off = 1; off < 64; off <<= 1) {
        int o = __shfl_up(sc, off, 64);
        if (lane >= off) sc += o;
    }
    __shared__ int wsums[4];
    if (lane == 63) wsums[wv] = sc;
    __syncthreads();
    int woff = 0;
    #pragma unroll
    for (int w = 0; w < 4; ++w) woff += (w < wv) ? wsums[w] : 0;
    int excl = woff + sc - s;
    int total = wsums[0] + wsums[1] + wsums[2] + wsums[3];

    float* pvb = pv + b * STRIDE;
    int* bpb = bpos + b * STRIDE;
    int r = excl;
    #pragma unroll
    for (int i = 0; i < 8; ++i) {
        if (f[i]) {
            int t = t0 + i;
            float p;
            if (t == 0) {
                p = 1.0f;
            } else {
                p = 1.0f / (1.0f + expf(-2.0f * blv[i]));
                p = fminf(fmaxf(p, 1e-4f), 1.0f - 1e-4f);
            }
            bpb[r] = t;
            pvb[r] = p;
            r += 1;
        }
    }
    if (tid == 0) nb[b] = total;
    for (int j = total + tid; j < STRIDE; j += 256) { bpb[j] = Lc; pvb[j] = 0.0f; }
}

// ---------------- Kernel 3: EMA over boundary tokens + span expansion ----------------
__global__ __launch_bounds__(128) void k3_ema(
    const float* __restrict__ H, const float* __restrict__ pv,
    const int* __restrict__ bpos, const int* __restrict__ nb,
    float* __restrict__ out)
{
    int b = blockIdx.x;
    int ch = blockIdx.y * 128 + threadIdx.x;
    const float* Hb = H + (size_t)b * Lc * Dc + ch;
    float* Ob = out + (size_t)b * Lc * Dc + ch;
    const float* pvb = pv + b * STRIDE;
    const int* bpb = bpos + b * STRIDE;
    int n = nb[b];
    int ng = (n + G - 1) / G;

    float xA[G], pA[G]; int tA[G + 1];
    #pragma unroll
    for (int i = 0; i < G; ++i) {
        int t = bpb[i];
        tA[i] = t;
        pA[i] = pvb[i];
        xA[i] = (t < Lc) ? Hb[(size_t)t * Dc] : 0.0f;
    }
    tA[G] = bpb[G];

    float h = 0.0f;
    for (int g = 0; g < ng; ++g) {
        int nbase = (g + 1) * G;
        float xB[G], pB[G]; int tB[G + 1];
        #pragma unroll
        for (int i = 0; i < G; ++i) {
            int t = bpb[nbase + i];
            tB[i] = t;
            pB[i] = pvb[nbase + i];
            xB[i] = (t < Lc) ? Hb[(size_t)t * Dc] : 0.0f;
        }
        tB[G] = bpb[nbase + G];
        #pragma unroll
        for (int i = 0; i < G; ++i) {
            h = (1.0f - pA[i]) * h + pA[i] * xA[i];
            int te = tA[i + 1];
            for (int tt = tA[i]; tt < te; ++tt) Ob[(size_t)tt * Dc] = h;
        }
        #pragma unroll
        for (int i = 0; i < G; ++i) { xA[i] = xB[i]; pA[i] = pB[i]; tA[i] = tB[i]; }
        tA[G] = tB[G];
    }
}

extern "C" void kernel_launch(void* const* d_in, const int* in_sizes, int n_in,
                              void* d_out, int out_size, void* d_ws, size_t ws_size,
                              hipStream_t stream)
{
    const float* H  = (const float*)d_in[0];
    const float* Wq = (const float*)d_in[1];
    const float* Wk = (const float*)d_in[2];
    const float* lt = (const float*)d_in[3];
    const float* bb = (const float*)d_in[4];
    const int* mask = (const int*)d_in[5];
    float* out = (float*)d_out;

    char* ws = (char*)d_ws;
    float* bl   = (float*)ws;                                     // 8*2048 floats
    float* pv   = (float*)(ws + (size_t)Bc * Lc * 4);
    int*   bpos = (int*)  (ws + (size_t)Bc * Lc * 4 + (size_t)Bc * STRIDE * 4);
    int*   nbp  = (int*)  (ws + (size_t)Bc * Lc * 4 + 2ull * Bc * STRIDE * 4);
    // chunk partials (9 x 16384 x 3 fp32 = 1.77 MB) live in d_out's head;
    // K3 fully overwrites d_out afterwards.
    float* partial = out;

    hipLaunchKernelGGL(k1_gemm, dim3(Bc * 16, NCHUNK), dim3(256), 0, stream,
                       H, Wq, Wk, partial);
    hipLaunchKernelGGL(k1b_reduce, dim3((Bc * Lc + 255) / 256), dim3(256), 0, stream,
                       partial, lt, bb, bl);
    hipLaunchKernelGGL(k2_boundary, dim3(Bc), dim3(256), 0, stream,
                       bl, mask, pv, bpos, nbp);
    hipLaunchKernelGGL(k3_ema, dim3(Bc, 9), dim3(128), 0, stream,
                       H, pv, bpos, nbp, out);
}

// Round 6
// 11437.434 us; speedup vs baseline: 2.1815x; 2.1815x over previous
//
#include <hip/hip_runtime.h>
#include <cstdint>
#include <cstddef>

#define Bc 8
#define Lc 2048
#define Dc 1152
#define STRIDE 2080
#define G 8

// ---- K1 GEMM geometry ----
#define T_BLK 128            // positions per block
#define KT 32                // K-tile (8 chunks of 4 floats)
#define NKS (Dc / KT)        // 36
#define NCHUNK 18            // e-chunks (grid.y); 64 e's each
#define ECH 64
#define HS_NU (129 * 8)      // 16B units: H tile 129 rows x 32 floats
#define W_NU (64 * 8)        // 16B units per W tile (64 rows x 32 floats)
#define BUF_F 8224           // floats per LDS buffer: H 4128 | Wq 2048 | Wk 2048
#define QS_OFF 4128
#define KS_OFF 6176

__device__ __forceinline__ void gld16(const float* g, float* l) {
    __builtin_amdgcn_global_load_lds(
        (const __attribute__((address_space(1))) void*)(g),
        (__attribute__((address_space(3))) void*)(l), 16, 0, 0);
}

#define DOT4(a, b) ((a).x*(b).x + (a).y*(b).y + (a).z*(b).z + (a).w*(b).w)

__device__ __forceinline__ void stage_tile(
    const float* __restrict__ Hb, const float* __restrict__ Wq,
    const float* __restrict__ Wk, float* bp, int t0, int eb, int kb, int tid)
{
    // H: unit u = rho*8+sl holds k-chunk (sl ^ (rho>>3))&7 of row rho
    for (int u = tid; u < HS_NU; u += 256) {
        int rho = u >> 3;
        int srck = kb + ((((u & 7) ^ (rho >> 3)) & 7) << 2);
        int grow = t0 - 1 + rho; if (grow > Lc - 1) grow = Lc - 1;
        gld16(Hb + (size_t)grow * Dc + srck, bp + u * 4);
    }
    // W: unit u = er*8+sl holds k-chunk (sl ^ er)&7 of e-row eb+er
    for (int u = tid; u < W_NU; u += 256) {
        int er = u >> 3;
        int srck = kb + ((((u & 7) ^ er) & 7) << 2);
        size_t off = (size_t)(eb + er) * Dc + srck;
        gld16(Wq + off, bp + QS_OFF + u * 4);
        gld16(Wk + off, bp + KS_OFF + u * 4);
    }
}

// ---------------- Kernel 1: tiled fp32 dual-GEMM + fused cos-stats ----------------
// Shared-row trick: LDS row rho (global t0-1+rho) feeds BOTH A_rho = Wq.h and
// B_rho = Wk.h. Thread (tx,ty): output rows 8ty+i (i=0..7), e-cols tx+16j
// (j=0..3). A[i] needs h[i], B[i] needs h[i+1] -> 9 H-reads + 8 W-reads per g.
// Slot swizzle (g^(rho>>3)) is uniform over a thread's 8 rows (rho>>3 == ty),
// so reads are one base register + immediate offsets. Stats qq=|A|^2, kk=|B|^2,
// qk=A.B are thread-local; tx-shuffle reduce at the end.
// ALL hot values are NAMED float4 SSA variables -- arrays of float4 get demoted
// to scratch by this compiler (rounds 3 & 5: 40-49 GB scratch traffic).
// Double-buffered LDS, one __syncthreads per k-step (drains the prefetch).
__global__ __launch_bounds__(256, 2) void k1_gemm(
    const float* __restrict__ H, const float* __restrict__ Wq,
    const float* __restrict__ Wk, float* __restrict__ partial)
{
    __shared__ __align__(16) float Lds[2 * BUF_F];   // 65792 B

    const int tid = threadIdx.x;
    const int bx = blockIdx.x;          // batch*16 + tile
    const int chunk = blockIdx.y;       // 0..17
    const int batch = bx >> 4;
    const int tile = bx & 15;
    const int t0 = 1 + tile * T_BLK;
    const float* Hb = H + (size_t)batch * Lc * Dc;
    const int eb = chunk * ECH;

    const int tx = tid & 15;
    const int ty = tid >> 4;

    float4 A0{0,0,0,0}, A1{0,0,0,0}, A2{0,0,0,0}, A3{0,0,0,0};
    float4 A4{0,0,0,0}, A5{0,0,0,0}, A6{0,0,0,0}, A7{0,0,0,0};
    float4 B0{0,0,0,0}, B1{0,0,0,0}, B2{0,0,0,0}, B3{0,0,0,0};
    float4 B4{0,0,0,0}, B5{0,0,0,0}, B6{0,0,0,0}, B7{0,0,0,0};

    stage_tile(Hb, Wq, Wk, Lds, t0, eb, 0, tid);
    __syncthreads();

    for (int ks = 0; ks < NKS; ++ks) {
        const float* bp = Lds + (ks & 1) * BUF_F;
        if (ks + 1 < NKS)
            stage_tile(Hb, Wq, Wk, Lds + ((ks + 1) & 1) * BUF_F, t0, eb,
                       (ks + 1) * KT, tid);

        #pragma unroll
        for (int g = 0; g < 8; ++g) {
            const float* hb  = bp + ty * 256 + (((g ^ ty) & 7) << 2);
            const float* hb8 = bp + ty * 256 + 256 + (((g ^ (ty + 1)) & 7) << 2);
            const float* wb  = bp + QS_OFF + tx * 32 + (((g ^ (tx & 7)) & 7) << 2);
            float4 h0 = *(const float4*)(hb);
            float4 h1 = *(const float4*)(hb + 32);
            float4 h2 = *(const float4*)(hb + 64);
            float4 h3 = *(const float4*)(hb + 96);
            float4 h4 = *(const float4*)(hb + 128);
            float4 h5 = *(const float4*)(hb + 160);
            float4 h6 = *(const float4*)(hb + 192);
            float4 h7 = *(const float4*)(hb + 224);
            float4 h8 = *(const float4*)(hb8);
            float4 q0 = *(const float4*)(wb);
            float4 q1 = *(const float4*)(wb + 512);
            float4 q2 = *(const float4*)(wb + 1024);
            float4 q3 = *(const float4*)(wb + 1536);
            float4 k0 = *(const float4*)(wb + 2048);   // Ks = Qs + 2048 floats
            float4 k1 = *(const float4*)(wb + 2560);
            float4 k2 = *(const float4*)(wb + 3072);
            float4 k3 = *(const float4*)(wb + 3584);
            #define STEP(i, hA, hB)                                            \
            {                                                                  \
                A##i.x += DOT4(hA, q0); A##i.y += DOT4(hA, q1);                \
                A##i.z += DOT4(hA, q2); A##i.w += DOT4(hA, q3);                \
                B##i.x += DOT4(hB, k0); B##i.y += DOT4(hB, k1);                \
                B##i.z += DOT4(hB, k2); B##i.w += DOT4(hB, k3);                \
            }
            STEP(0, h0, h1) STEP(1, h1, h2) STEP(2, h2, h3) STEP(3, h3, h4)
            STEP(4, h4, h5) STEP(5, h5, h6) STEP(6, h6, h7) STEP(7, h7, h8)
            #undef STEP
        }
        __syncthreads();   // drains prefetch vmcnt + protects buffer swap
    }

    // stats per output row, then reduce across the 16 tx-lanes
    float qq0, qq1, qq2, qq3, qq4, qq5, qq6, qq7;
    float kk0, kk1, kk2, kk3, kk4, kk5, kk6, kk7;
    float qk0, qk1, qk2, qk3, qk4, qk5, qk6, qk7;
    #define FOLD(i)                                                            \
    {                                                                          \
        qq##i = DOT4(A##i, A##i);                                              \
        kk##i = DOT4(B##i, B##i);                                              \
        qk##i = DOT4(A##i, B##i);                                              \
    }
    FOLD(0) FOLD(1) FOLD(2) FOLD(3) FOLD(4) FOLD(5) FOLD(6) FOLD(7)
    #undef FOLD
    #define RED(v)                                                             \
    {                                                                          \
        v += __shfl_xor(v, 1, 64); v += __shfl_xor(v, 2, 64);                  \
        v += __shfl_xor(v, 4, 64); v += __shfl_xor(v, 8, 64);                  \
    }
    RED(qq0) RED(qq1) RED(qq2) RED(qq3) RED(qq4) RED(qq5) RED(qq6) RED(qq7)
    RED(kk0) RED(kk1) RED(kk2) RED(kk3) RED(kk4) RED(kk5) RED(kk6) RED(kk7)
    RED(qk0) RED(qk1) RED(qk2) RED(qk3) RED(qk4) RED(qk5) RED(qk6) RED(qk7)
    #undef RED

    if (tx == 0) {
        #define STORE(i)                                                       \
        {                                                                      \
            int t = t0 + 8 * ty + i;                                           \
            if (t < Lc) {                                                      \
                size_t idx = (((size_t)chunk * Bc + batch) * Lc + t) * 3;      \
                partial[idx + 0] = qq##i;                                      \
                partial[idx + 1] = kk##i;                                      \
                partial[idx + 2] = qk##i;                                      \
            }                                                                  \
        }
        STORE(0) STORE(1) STORE(2) STORE(3) STORE(4) STORE(5) STORE(6) STORE(7)
        #undef STORE
    }
}

// ---------------- Kernel 1b: deterministic chunk-reduce -> bl ----------------
__global__ __launch_bounds__(256) void k1b_reduce(
    const float* __restrict__ partial, const float* __restrict__ ltemp,
    const float* __restrict__ bbias, float* __restrict__ bl_out)
{
    int idx = blockIdx.x * 256 + threadIdx.x;   // batch*Lc + t
    if (idx >= Bc * Lc) return;
    int t = idx & (Lc - 1);
    if (t == 0) return;
    float qq = 0.f, kk = 0.f, qk = 0.f;
    #pragma unroll
    for (int c = 0; c < NCHUNK; ++c) {
        size_t p = ((size_t)c * Bc * Lc + idx) * 3;
        qq += partial[p];
        kk += partial[p + 1];
        qk += partial[p + 2];
    }
    float T = expf(ltemp[0]);
    T = fminf(fmaxf(T, 0.1f), 10.0f);
    float den = fmaxf(sqrtf(qq), 1e-12f) * fmaxf(sqrtf(kk), 1e-12f);
    bl_out[idx] = (1.0f - qk / den) * T + bbias[0];
}

// ---------------- Kernel 2: boundary decision + stable compaction ----------------
__global__ __launch_bounds__(256) void k2_boundary(
    const float* __restrict__ bl_in, const int* __restrict__ mask,
    float* __restrict__ pv, int* __restrict__ bpos, int* __restrict__ nb)
{
    int b = blockIdx.x;
    int tid = threadIdx.x;
    const float* blb = bl_in + b * Lc;
    const int* mb = mask + b * Lc;

    float blv[8]; int f[8];
    int t0 = tid * 8;
    int s = 0;
    #pragma unroll
    for (int i = 0; i < 8; ++i) {
        int t = t0 + i;
        float v = (t == 0) ? 10.0f : blb[t];
        blv[i] = v;
        f[i] = (v > 0.0f && mb[t] != 0) ? 1 : 0;
        s += f[i];
    }
    int lane = tid & 63, wv = tid >> 6;
    int sc = s;
    #pragma unroll
    for (int off = 1; off < 64; off <<= 1) {
        int o = __shfl_up(sc, off, 64);
        if (lane >= off) sc += o;
    }
    __shared__ int wsums[4];
    if (lane == 63) wsums[wv] = sc;
    __syncthreads();
    int woff = 0;
    #pragma unroll
    for (int w = 0; w < 4; ++w) woff += (w < wv) ? wsums[w] : 0;
    int excl = woff + sc - s;
    int total = wsums[0] + wsums[1] + wsums[2] + wsums[3];

    float* pvb = pv + b * STRIDE;
    int* bpb = bpos + b * STRIDE;
    int r = excl;
    #pragma unroll
    for (int i = 0; i < 8; ++i) {
        if (f[i]) {
            int t = t0 + i;
            float p;
            if (t == 0) {
                p = 1.0f;
            } else {
                p = 1.0f / (1.0f + expf(-2.0f * blv[i]));
                p = fminf(fmaxf(p, 1e-4f), 1.0f - 1e-4f);
            }
            bpb[r] = t;
            pvb[r] = p;
            r += 1;
        }
    }
    if (tid == 0) nb[b] = total;
    for (int j = total + tid; j < STRIDE; j += 256) { bpb[j] = Lc; pvb[j] = 0.0f; }
}

// ---------------- Kernel 3: EMA over boundary tokens + span expansion ----------------
__global__ __launch_bounds__(128) void k3_ema(
    const float* __restrict__ H, const float* __restrict__ pv,
    const int* __restrict__ bpos, const int* __restrict__ nb,
    float* __restrict__ out)
{
    int b = blockIdx.x;
    int ch = blockIdx.y * 128 + threadIdx.x;
    const float* Hb = H + (size_t)b * Lc * Dc + ch;
    float* Ob = out + (size_t)b * Lc * Dc + ch;
    const float* pvb = pv + b * STRIDE;
    const int* bpb = bpos + b * STRIDE;
    int n = nb[b];
    int ng = (n + G - 1) / G;

    float xA[G], pA[G]; int tA[G + 1];
    #pragma unroll
    for (int i = 0; i < G; ++i) {
        int t = bpb[i];
        tA[i] = t;
        pA[i] = pvb[i];
        xA[i] = (t < Lc) ? Hb[(size_t)t * Dc] : 0.0f;
    }
    tA[G] = bpb[G];

    float h = 0.0f;
    for (int g = 0; g < ng; ++g) {
        int nbase = (g + 1) * G;
        float xB[G], pB[G]; int tB[G + 1];
        #pragma unroll
        for (int i = 0; i < G; ++i) {
            int t = bpb[nbase + i];
            tB[i] = t;
            pB[i] = pvb[nbase + i];
            xB[i] = (t < Lc) ? Hb[(size_t)t * Dc] : 0.0f;
        }
        tB[G] = bpb[nbase + G];
        #pragma unroll
        for (int i = 0; i < G; ++i) {
            h = (1.0f - pA[i]) * h + pA[i] * xA[i];
            int te = tA[i + 1];
            for (int tt = tA[i]; tt < te; ++tt) Ob[(size_t)tt * Dc] = h;
        }
        #pragma unroll
        for (int i = 0; i < G; ++i) { xA[i] = xB[i]; pA[i] = pB[i]; tA[i] = tB[i]; }
        tA[G] = tB[G];
    }
}

extern "C" void kernel_launch(void* const* d_in, const int* in_sizes, int n_in,
                              void* d_out, int out_size, void* d_ws, size_t ws_size,
                              hipStream_t stream)
{
    const float* H  = (const float*)d_in[0];
    const float* Wq = (const float*)d_in[1];
    const float* Wk = (const float*)d_in[2];
    const float* lt = (const float*)d_in[3];
    const float* bb = (const float*)d_in[4];
    const int* mask = (const int*)d_in[5];
    float* out = (float*)d_out;

    char* ws = (char*)d_ws;
    float* bl   = (float*)ws;                                     // 8*2048 floats
    float* pv   = (float*)(ws + (size_t)Bc * Lc * 4);
    int*   bpos = (int*)  (ws + (size_t)Bc * Lc * 4 + (size_t)Bc * STRIDE * 4);
    int*   nbp  = (int*)  (ws + (size_t)Bc * Lc * 4 + 2ull * Bc * STRIDE * 4);
    // chunk partials (18 x 16384 x 3 fp32 = 3.5 MB) live in d_out's head;
    // K3 fully overwrites d_out afterwards.
    float* partial = out;

    hipLaunchKernelGGL(k1_gemm, dim3(Bc * 16, NCHUNK), dim3(256), 0, stream,
                       H, Wq, Wk, partial);
    hipLaunchKernelGGL(k1b_reduce, dim3((Bc * Lc + 255) / 256), dim3(256), 0, stream,
                       partial, lt, bb, bl);
    hipLaunchKernelGGL(k2_boundary, dim3(Bc), dim3(256), 0, stream,
                       bl, mask, pv, bpos, nbp);
    hipLaunchKernelGGL(k3_ema, dim3(Bc, 9), dim3(128), 0, stream,
                       H, pv, bpos, nbp, out);
}

// Round 7
// 11331.886 us; speedup vs baseline: 2.2018x; 1.0093x over previous
//
#include <hip/hip_runtime.h>
#include <cstdint>
#include <cstddef>

#define Bc 8
#define Lc 2048
#define Dc 1152
#define STRIDE 2080
#define G 8

// ---- K1 GEMM geometry ----
#define T_BLK 128            // positions per block
#define KT 32                // K-tile (8 chunks of 4 floats)
#define NKS (Dc / KT)        // 36
#define NCHUNK 18            // e-chunks (grid.y); 64 e's each
#define ECH 64
#define HS_NU (129 * 8)      // 16B units: H tile 129 rows x 32 floats
#define W_NU (64 * 8)        // 16B units per W tile (64 rows x 32 floats)
#define BUF_F 8224           // floats per LDS buffer: H 4128 | Wq 2048 | Wk 2048
#define QS_OFF 4128
#define KS_OFF 6176

__device__ __forceinline__ void gld16(const float* g, float* l) {
    __builtin_amdgcn_global_load_lds(
        (const __attribute__((address_space(1))) void*)(g),
        (__attribute__((address_space(3))) void*)(l), 16, 0, 0);
}

#define DOT4(a, b) ((a).x*(b).x + (a).y*(b).y + (a).z*(b).z + (a).w*(b).w)

__device__ __forceinline__ void stage_tile(
    const float* __restrict__ Hb, const float* __restrict__ Wq,
    const float* __restrict__ Wk, float* bp, int t0, int eb, int kb, int tid)
{
    // H: unit u = rho*8+sl holds k-chunk (sl ^ (rho>>3))&7 of row rho
    for (int u = tid; u < HS_NU; u += 256) {
        int rho = u >> 3;
        int srck = kb + ((((u & 7) ^ (rho >> 3)) & 7) << 2);
        int grow = t0 - 1 + rho; if (grow > Lc - 1) grow = Lc - 1;
        gld16(Hb + (size_t)grow * Dc + srck, bp + u * 4);
    }
    // W: unit u = er*8+sl holds k-chunk (sl ^ er)&7 of e-row eb+er
    for (int u = tid; u < W_NU; u += 256) {
        int er = u >> 3;
        int srck = kb + ((((u & 7) ^ er) & 7) << 2);
        size_t off = (size_t)(eb + er) * Dc + srck;
        gld16(Wq + off, bp + QS_OFF + u * 4);
        gld16(Wk + off, bp + KS_OFF + u * 4);
    }
}

// ---------------- Kernel 1: tiled fp32 dual-GEMM + fused cos-stats ----------------
// Shared-row trick: LDS row rho (global t0-1+rho) feeds BOTH A_rho = Wq.h and
// B_rho = Wk.h. Thread (tx,ty): output rows 8ty+i, e-cols tx+16j (j=0..3).
// H fragments are a ROLLING PAIR (hp,hc): STEP(i) uses h[i],h[i+1], then
// hp=hc -- keeps the mid-loop live set at ~116 floats (64 acc + 8 h + 32 W +
// bases). HARD CONSTRAINT (rounds 3/5/6): this allocator never exceeds 128
// VGPRs -- it spills to scratch instead (26-49 GB of HBM scratch traffic,
// 13x slowdowns). Named SSA values only; live-set must fit under 128.
// Slot swizzle (g^(rho>>3)) is uniform per thread -> one base + immediates.
// Double-buffered LDS, one __syncthreads per k-step (drains prefetch vmcnt).
__global__ __launch_bounds__(256, 2) void k1_gemm(
    const float* __restrict__ H, const float* __restrict__ Wq,
    const float* __restrict__ Wk, float* __restrict__ partial)
{
    __shared__ __align__(16) float Lds[2 * BUF_F];   // 65792 B

    const int tid = threadIdx.x;
    const int bx = blockIdx.x;          // batch*16 + tile
    const int chunk = blockIdx.y;       // 0..17
    const int batch = bx >> 4;
    const int tile = bx & 15;
    const int t0 = 1 + tile * T_BLK;
    const float* Hb = H + (size_t)batch * Lc * Dc;
    const int eb = chunk * ECH;

    const int tx = tid & 15;
    const int ty = tid >> 4;

    float4 A0{0,0,0,0}, A1{0,0,0,0}, A2{0,0,0,0}, A3{0,0,0,0};
    float4 A4{0,0,0,0}, A5{0,0,0,0}, A6{0,0,0,0}, A7{0,0,0,0};
    float4 B0{0,0,0,0}, B1{0,0,0,0}, B2{0,0,0,0}, B3{0,0,0,0};
    float4 B4{0,0,0,0}, B5{0,0,0,0}, B6{0,0,0,0}, B7{0,0,0,0};

    stage_tile(Hb, Wq, Wk, Lds, t0, eb, 0, tid);
    __syncthreads();

    for (int ks = 0; ks < NKS; ++ks) {
        const float* bp = Lds + (ks & 1) * BUF_F;
        if (ks + 1 < NKS)
            stage_tile(Hb, Wq, Wk, Lds + ((ks + 1) & 1) * BUF_F, t0, eb,
                       (ks + 1) * KT, tid);

        #pragma unroll
        for (int g = 0; g < 8; ++g) {
            const float* hb  = bp + ty * 256 + (((g ^ ty) & 7) << 2);
            const float* hb8 = bp + ty * 256 + 256 + (((g ^ (ty + 1)) & 7) << 2);
            const float* wb  = bp + QS_OFF + tx * 32 + (((g ^ (tx & 7)) & 7) << 2);
            float4 q0 = *(const float4*)(wb);
            float4 q1 = *(const float4*)(wb + 512);
            float4 q2 = *(const float4*)(wb + 1024);
            float4 q3 = *(const float4*)(wb + 1536);
            float4 k0 = *(const float4*)(wb + 2048);   // Ks = Qs + 2048 floats
            float4 k1 = *(const float4*)(wb + 2560);
            float4 k2 = *(const float4*)(wb + 3072);
            float4 k3 = *(const float4*)(wb + 3584);
            float4 hp = *(const float4*)(hb);
            float4 hc;
            #define STEP(i, NEXT)                                              \
            {                                                                  \
                hc = *(const float4*)(NEXT);                                   \
                A##i.x += DOT4(hp, q0); A##i.y += DOT4(hp, q1);                \
                A##i.z += DOT4(hp, q2); A##i.w += DOT4(hp, q3);                \
                B##i.x += DOT4(hc, k0); B##i.y += DOT4(hc, k1);                \
                B##i.z += DOT4(hc, k2); B##i.w += DOT4(hc, k3);                \
                hp = hc;                                                       \
            }
            STEP(0, hb + 32)  STEP(1, hb + 64)  STEP(2, hb + 96)
            STEP(3, hb + 128) STEP(4, hb + 160) STEP(5, hb + 192)
            STEP(6, hb + 224) STEP(7, hb8)
            #undef STEP
        }
        __syncthreads();   // drains prefetch vmcnt + protects buffer swap
    }

    // stats per output row, then reduce across the 16 tx-lanes
    float qq0, qq1, qq2, qq3, qq4, qq5, qq6, qq7;
    float kk0, kk1, kk2, kk3, kk4, kk5, kk6, kk7;
    float qk0, qk1, qk2, qk3, qk4, qk5, qk6, qk7;
    #define FOLD(i)                                                            \
    {                                                                          \
        qq##i = DOT4(A##i, A##i);                                              \
        kk##i = DOT4(B##i, B##i);                                              \
        qk##i = DOT4(A##i, B##i);                                              \
    }
    FOLD(0) FOLD(1) FOLD(2) FOLD(3) FOLD(4) FOLD(5) FOLD(6) FOLD(7)
    #undef FOLD
    #define RED(v)                                                             \
    {                                                                          \
        v += __shfl_xor(v, 1, 64); v += __shfl_xor(v, 2, 64);                  \
        v += __shfl_xor(v, 4, 64); v += __shfl_xor(v, 8, 64);                  \
    }
    RED(qq0) RED(qq1) RED(qq2) RED(qq3) RED(qq4) RED(qq5) RED(qq6) RED(qq7)
    RED(kk0) RED(kk1) RED(kk2) RED(kk3) RED(kk4) RED(kk5) RED(kk6) RED(kk7)
    RED(qk0) RED(qk1) RED(qk2) RED(qk3) RED(qk4) RED(qk5) RED(qk6) RED(qk7)
    #undef RED

    if (tx == 0) {
        #define STORE(i)                                                       \
        {                                                                      \
            int t = t0 + 8 * ty + i;                                           \
            if (t < Lc) {                                                      \
                size_t idx = (((size_t)chunk * Bc + batch) * Lc + t) * 3;      \
                partial[idx + 0] = qq##i;                                      \
                partial[idx + 1] = kk##i;                                      \
                partial[idx + 2] = qk##i;                                      \
            }                                                                  \
        }
        STORE(0) STORE(1) STORE(2) STORE(3) STORE(4) STORE(5) STORE(6) STORE(7)
        #undef STORE
    }
}

// ---------------- Kernel 1b: deterministic chunk-reduce -> bl ----------------
__global__ __launch_bounds__(256) void k1b_reduce(
    const float* __restrict__ partial, const float* __restrict__ ltemp,
    const float* __restrict__ bbias, float* __restrict__ bl_out)
{
    int idx = blockIdx.x * 256 + threadIdx.x;   // batch*Lc + t
    if (idx >= Bc * Lc) return;
    int t = idx & (Lc - 1);
    if (t == 0) return;
    float qq = 0.f, kk = 0.f, qk = 0.f;
    #pragma unroll
    for (int c = 0; c < NCHUNK; ++c) {
        size_t p = ((size_t)c * Bc * Lc + idx) * 3;
        qq += partial[p];
        kk += partial[p + 1];
        qk += partial[p + 2];
    }
    float T = expf(ltemp[0]);
    T = fminf(fmaxf(T, 0.1f), 10.0f);
    float den = fmaxf(sqrtf(qq), 1e-12f) * fmaxf(sqrtf(kk), 1e-12f);
    bl_out[idx] = (1.0f - qk / den) * T + bbias[0];
}

// ---------------- Kernel 2: boundary decision + stable compaction ----------------
__global__ __launch_bounds__(256) void k2_boundary(
    const float* __restrict__ bl_in, const int* __restrict__ mask,
    float* __restrict__ pv, int* __restrict__ bpos, int* __restrict__ nb)
{
    int b = blockIdx.x;
    int tid = threadIdx.x;
    const float* blb = bl_in + b * Lc;
    const int* mb = mask + b * Lc;

    float blv[8]; int f[8];
    int t0 = tid * 8;
    int s = 0;
    #pragma unroll
    for (int i = 0; i < 8; ++i) {
        int t = t0 + i;
        float v = (t == 0) ? 10.0f : blb[t];
        blv[i] = v;
        f[i] = (v > 0.0f && mb[t] != 0) ? 1 : 0;
        s += f[i];
    }
    int lane = tid & 63, wv = tid >> 6;
    int sc = s;
    #pragma unroll
    for (int off = 1; off < 64; off <<= 1) {
        int o = __shfl_up(sc, off, 64);
        if (lane >= off) sc += o;
    }
    __shared__ int wsums[4];
    if (lane == 63) wsums[wv] = sc;
    __syncthreads();
    int woff = 0;
    #pragma unroll
    for (int w = 0; w < 4; ++w) woff += (w < wv) ? wsums[w] : 0;
    int excl = woff + sc - s;
    int total = wsums[0] + wsums[1] + wsums[2] + wsums[3];

    float* pvb = pv + b * STRIDE;
    int* bpb = bpos + b * STRIDE;
    int r = excl;
    #pragma unroll
    for (int i = 0; i < 8; ++i) {
        if (f[i]) {
            int t = t0 + i;
            float p;
            if (t == 0) {
                p = 1.0f;
            } else {
                p = 1.0f / (1.0f + expf(-2.0f * blv[i]));
                p = fminf(fmaxf(p, 1e-4f), 1.0f - 1e-4f);
            }
            bpb[r] = t;
            pvb[r] = p;
            r += 1;
        }
    }
    if (tid == 0) nb[b] = total;
    for (int j = total + tid; j < STRIDE; j += 256) { bpb[j] = Lc; pvb[j] = 0.0f; }
}

// ---------------- Kernel 3: EMA over boundary tokens + span expansion ----------------
__global__ __launch_bounds__(128) void k3_ema(
    const float* __restrict__ H, const float* __restrict__ pv,
    const int* __restrict__ bpos, const int* __restrict__ nb,
    float* __restrict__ out)
{
    int b = blockIdx.x;
    int ch = blockIdx.y * 128 + threadIdx.x;
    const float* Hb = H + (size_t)b * Lc * Dc + ch;
    float* Ob = out + (size_t)b * Lc * Dc + ch;
    const float* pvb = pv + b * STRIDE;
    const int* bpb = bpos + b * STRIDE;
    int n = nb[b];
    int ng = (n + G - 1) / G;

    float xA[G], pA[G]; int tA[G + 1];
    #pragma unroll
    for (int i = 0; i < G; ++i) {
        int t = bpb[i];
        tA[i] = t;
        pA[i] = pvb[i];
        xA[i] = (t < Lc) ? Hb[(size_t)t * Dc] : 0.0f;
    }
    tA[G] = bpb[G];

    float h = 0.0f;
    for (int g = 0; g < ng; ++g) {
        int nbase = (g + 1) * G;
        float xB[G], pB[G]; int tB[G + 1];
        #pragma unroll
        for (int i = 0; i < G; ++i) {
            int t = bpb[nbase + i];
            tB[i] = t;
            pB[i] = pvb[nbase + i];
            xB[i] = (t < Lc) ? Hb[(size_t)t * Dc] : 0.0f;
        }
        tB[G] = bpb[nbase + G];
        #pragma unroll
        for (int i = 0; i < G; ++i) {
            h = (1.0f - pA[i]) * h + pA[i] * xA[i];
            int te = tA[i + 1];
            for (int tt = tA[i]; tt < te; ++tt) Ob[(size_t)tt * Dc] = h;
        }
        #pragma unroll
        for (int i = 0; i < G; ++i) { xA[i] = xB[i]; pA[i] = pB[i]; tA[i] = tB[i]; }
        tA[G] = tB[G];
    }
}

extern "C" void kernel_launch(void* const* d_in, const int* in_sizes, int n_in,
                              void* d_out, int out_size, void* d_ws, size_t ws_size,
                              hipStream_t stream)
{
    const float* H  = (const float*)d_in[0];
    const float* Wq = (const float*)d_in[1];
    const float* Wk = (const float*)d_in[2];
    const float* lt = (const float*)d_in[3];
    const float* bb = (const float*)d_in[4];
    const int* mask = (const int*)d_in[5];
    float* out = (float*)d_out;

    char* ws = (char*)d_ws;
    float* bl   = (float*)ws;                                     // 8*2048 floats
    float* pv   = (float*)(ws + (size_t)Bc * Lc * 4);
    int*   bpos = (int*)  (ws + (size_t)Bc * Lc * 4 + (size_t)Bc * STRIDE * 4);
    int*   nbp  = (int*)  (ws + (size_t)Bc * Lc * 4 + 2ull * Bc * STRIDE * 4);
    // chunk partials (18 x 16384 x 3 fp32 = 3.5 MB) live in d_out's head;
    // K3 fully overwrites d_out afterwards.
    float* partial = out;

    hipLaunchKernelGGL(k1_gemm, dim3(Bc * 16, NCHUNK), dim3(256), 0, stream,
                       H, Wq, Wk, partial);
    hipLaunchKernelGGL(k1b_reduce, dim3((Bc * Lc + 255) / 256), dim3(256), 0, stream,
                       partial, lt, bb, bl);
    hipLaunchKernelGGL(k2_boundary, dim3(Bc), dim3(256), 0, stream,
                       bl, mask, pv, bpos, nbp);
    hipLaunchKernelGGL(k3_ema, dim3(Bc, 9), dim3(128), 0, stream,
                       H, pv, bpos, nbp, out);
}

// Round 8
// 1335.233 us; speedup vs baseline: 18.6865x; 8.4868x over previous
//
#include <hip/hip_runtime.h>
#include <cstdint>
#include <cstddef>

#define Bc 8
#define Lc 2048
#define Dc 1152
#define STRIDE 2080
#define G 8

// ---- K1 GEMM geometry ----
#define T_BLK 128            // positions per block
#define KT 32                // K-tile (8 chunks of 4 floats)
#define NKS (Dc / KT)        // 36
#define NCHUNK 18            // e-chunks (grid.y); 64 e's each
#define ECH 64
#define HS_NU (129 * 8)      // 16B units: H tile 129 rows x 32 floats
#define W_NU (64 * 8)        // 16B units per W tile
#define QS_OFF 4128          // float offsets inside the single LDS buffer
#define KS_OFF 6176
#define BUF_F 8224           // 32896 B total

__device__ __forceinline__ void gld16(const float* g, float* l) {
    __builtin_amdgcn_global_load_lds(
        (const __attribute__((address_space(1))) void*)(g),
        (__attribute__((address_space(3))) void*)(l), 16, 0, 0);
}

// ---------------- Kernel 1: tiled fp32 dual-GEMM + fused cos-stats ----------------
// Structure notes (hard-won over rounds 3-7):
//  * SINGLE-buffer LDS, stage -> __syncthreads -> compute -> __syncthreads.
//    The barrier after staging fences the staging-address registers away from
//    the compute's peak pressure. Double-buffer prefetch (r6/r7) made the
//    scheduler stretch those addresses across the g-loop -> spill -> 30 GB
//    of scratch traffic. This allocator NEVER goes above 128 VGPRs.
//  * A-phase / B-phase split per g: only 4 W-float4 live at once. Worst-case
//    hoisting = 64 acc + 16 W + 32 h + misc < 128.
//  * Serial fmaf() chains: `a += x*y + z*w + ...` does NOT contract without
//    fast-math (mul+add trees, ~2x VALU). fmaf forces v_fma_f32.
//  * Shared-row: LDS row rho feeds A_rho (q[t0+rho]) and B_rho (k[t0+rho-1]).
//    Thread (tx,ty): rows 8ty+i, e-cols tx+16j. Swizzle slot g^(rho>>3) is
//    uniform over a thread's rows (rho>>3 == ty) -> base reg + imm offsets.
__global__ __launch_bounds__(256, 2) void k1_gemm(
    const float* __restrict__ H, const float* __restrict__ Wq,
    const float* __restrict__ Wk, float* __restrict__ partial)
{
    __shared__ __align__(16) float Lds[BUF_F];

    const int tid = threadIdx.x;
    const int bx = blockIdx.x;          // batch*16 + tile
    const int chunk = blockIdx.y;       // 0..17
    const int batch = bx >> 4;
    const int tile = bx & 15;
    const int t0 = 1 + tile * T_BLK;
    const float* Hb = H + (size_t)batch * Lc * Dc;
    const int eb = chunk * ECH;

    const int tx = tid & 15;
    const int ty = tid >> 4;

    float4 A0{0,0,0,0}, A1{0,0,0,0}, A2{0,0,0,0}, A3{0,0,0,0};
    float4 A4{0,0,0,0}, A5{0,0,0,0}, A6{0,0,0,0}, A7{0,0,0,0};
    float4 B0{0,0,0,0}, B1{0,0,0,0}, B2{0,0,0,0}, B3{0,0,0,0};
    float4 B4{0,0,0,0}, B5{0,0,0,0}, B6{0,0,0,0}, B7{0,0,0,0};

    for (int ks = 0; ks < NKS; ++ks) {
        const int kb = ks * KT;
        // stage H window: unit u = rho*8+sl holds k-chunk (sl ^ (rho>>3))&7
        for (int u = tid; u < HS_NU; u += 256) {
            int rho = u >> 3;
            int srck = kb + ((((u & 7) ^ (rho >> 3)) & 7) << 2);
            int grow = t0 - 1 + rho; if (grow > Lc - 1) grow = Lc - 1;
            gld16(Hb + (size_t)grow * Dc + srck, Lds + u * 4);
        }
        // stage Wq/Wk: unit u = er*8+sl holds k-chunk (sl ^ er)&7 of row eb+er
        for (int u = tid; u < W_NU; u += 256) {
            int er = u >> 3;
            int srck = kb + ((((u & 7) ^ er) & 7) << 2);
            size_t off = (size_t)(eb + er) * Dc + srck;
            gld16(Wq + off, Lds + QS_OFF + u * 4);
            gld16(Wk + off, Lds + KS_OFF + u * 4);
        }
        __syncthreads();   // drains vmcnt; fences staging-addr registers

        #pragma unroll
        for (int g = 0; g < 8; ++g) {
            const float* hbA = Lds + ty * 256 + (((g ^ ty) & 7) << 2);
            const float* wb  = Lds + QS_OFF + (tx << 5) + (((g ^ (tx & 7)) & 7) << 2);
            // ---- A phase: q columns, rows 8ty..8ty+7 ----
            {
                float4 q0 = *(const float4*)(wb);
                float4 q1 = *(const float4*)(wb + 512);
                float4 q2 = *(const float4*)(wb + 1024);
                float4 q3 = *(const float4*)(wb + 1536);
                #define ASTEP(i)                                               \
                {                                                              \
                    float4 h = *(const float4*)(hbA + (i) * 32);               \
                    A##i.x = fmaf(h.x, q0.x, A##i.x);                          \
                    A##i.x = fmaf(h.y, q0.y, A##i.x);                          \
                    A##i.x = fmaf(h.z, q0.z, A##i.x);                          \
                    A##i.x = fmaf(h.w, q0.w, A##i.x);                          \
                    A##i.y = fmaf(h.x, q1.x, A##i.y);                          \
                    A##i.y = fmaf(h.y, q1.y, A##i.y);                          \
                    A##i.y = fmaf(h.z, q1.z, A##i.y);                          \
                    A##i.y = fmaf(h.w, q1.w, A##i.y);                          \
                    A##i.z = fmaf(h.x, q2.x, A##i.z);                          \
                    A##i.z = fmaf(h.y, q2.y, A##i.z);                          \
                    A##i.z = fmaf(h.z, q2.z, A##i.z);                          \
                    A##i.z = fmaf(h.w, q2.w, A##i.z);                          \
                    A##i.w = fmaf(h.x, q3.x, A##i.w);                          \
                    A##i.w = fmaf(h.y, q3.y, A##i.w);                          \
                    A##i.w = fmaf(h.z, q3.z, A##i.w);                          \
                    A##i.w = fmaf(h.w, q3.w, A##i.w);                          \
                }
                ASTEP(0) ASTEP(1) ASTEP(2) ASTEP(3)
                ASTEP(4) ASTEP(5) ASTEP(6) ASTEP(7)
                #undef ASTEP
            }
            // ---- B phase: k columns, rows 8ty+1..8ty+8 ----
            {
                float4 k0 = *(const float4*)(wb + 2048);
                float4 k1 = *(const float4*)(wb + 2560);
                float4 k2 = *(const float4*)(wb + 3072);
                float4 k3 = *(const float4*)(wb + 3584);
                const float* hb8 = Lds + (ty + 1) * 256 + (((g ^ (ty + 1)) & 7) << 2);
                #define BSTEP(i, HP)                                           \
                {                                                              \
                    float4 h = *(const float4*)(HP);                           \
                    B##i.x = fmaf(h.x, k0.x, B##i.x);                          \
                    B##i.x = fmaf(h.y, k0.y, B##i.x);                          \
                    B##i.x = fmaf(h.z, k0.z, B##i.x);                          \
                    B##i.x = fmaf(h.w, k0.w, B##i.x);                          \
                    B##i.y = fmaf(h.x, k1.x, B##i.y);                          \
                    B##i.y = fmaf(h.y, k1.y, B##i.y);                          \
                    B##i.y = fmaf(h.z, k1.z, B##i.y);                          \
                    B##i.y = fmaf(h.w, k1.w, B##i.y);                          \
                    B##i.z = fmaf(h.x, k2.x, B##i.z);                          \
                    B##i.z = fmaf(h.y, k2.y, B##i.z);                          \
                    B##i.z = fmaf(h.z, k2.z, B##i.z);                          \
                    B##i.z = fmaf(h.w, k2.w, B##i.z);                          \
                    B##i.w = fmaf(h.x, k3.x, B##i.w);                          \
                    B##i.w = fmaf(h.y, k3.y, B##i.w);                          \
                    B##i.w = fmaf(h.z, k3.z, B##i.w);                          \
                    B##i.w = fmaf(h.w, k3.w, B##i.w);                          \
                }
                BSTEP(0, hbA + 32)  BSTEP(1, hbA + 64)  BSTEP(2, hbA + 96)
                BSTEP(3, hbA + 128) BSTEP(4, hbA + 160) BSTEP(5, hbA + 192)
                BSTEP(6, hbA + 224) BSTEP(7, hb8)
                #undef BSTEP
            }
        }
        __syncthreads();
    }

    // stats per output row, then reduce across the 16 tx-lanes
    #define DOT4(a, b) ((a).x*(b).x + (a).y*(b).y + (a).z*(b).z + (a).w*(b).w)
    float qq0, qq1, qq2, qq3, qq4, qq5, qq6, qq7;
    float kk0, kk1, kk2, kk3, kk4, kk5, kk6, kk7;
    float qk0, qk1, qk2, qk3, qk4, qk5, qk6, qk7;
    #define FOLD(i)                                                            \
    {                                                                          \
        qq##i = DOT4(A##i, A##i);                                              \
        kk##i = DOT4(B##i, B##i);                                              \
        qk##i = DOT4(A##i, B##i);                                              \
    }
    FOLD(0) FOLD(1) FOLD(2) FOLD(3) FOLD(4) FOLD(5) FOLD(6) FOLD(7)
    #undef FOLD
    #define RED(v)                                                             \
    {                                                                          \
        v += __shfl_xor(v, 1, 64); v += __shfl_xor(v, 2, 64);                  \
        v += __shfl_xor(v, 4, 64); v += __shfl_xor(v, 8, 64);                  \
    }
    RED(qq0) RED(qq1) RED(qq2) RED(qq3) RED(qq4) RED(qq5) RED(qq6) RED(qq7)
    RED(kk0) RED(kk1) RED(kk2) RED(kk3) RED(kk4) RED(kk5) RED(kk6) RED(kk7)
    RED(qk0) RED(qk1) RED(qk2) RED(qk3) RED(qk4) RED(qk5) RED(qk6) RED(qk7)
    #undef RED

    if (tx == 0) {
        #define STORE(i)                                                       \
        {                                                                      \
            int t = t0 + 8 * ty + i;                                           \
            if (t < Lc) {                                                      \
                size_t idx = (((size_t)chunk * Bc + batch) * Lc + t) * 3;      \
                partial[idx + 0] = qq##i;                                      \
                partial[idx + 1] = kk##i;                                      \
                partial[idx + 2] = qk##i;                                      \
            }                                                                  \
        }
        STORE(0) STORE(1) STORE(2) STORE(3) STORE(4) STORE(5) STORE(6) STORE(7)
        #undef STORE
    }
}

// ---------------- Kernel 1b: deterministic chunk-reduce -> bl ----------------
__global__ __launch_bounds__(256) void k1b_reduce(
    const float* __restrict__ partial, const float* __restrict__ ltemp,
    const float* __restrict__ bbias, float* __restrict__ bl_out)
{
    int idx = blockIdx.x * 256 + threadIdx.x;   // batch*Lc + t
    if (idx >= Bc * Lc) return;
    int t = idx & (Lc - 1);
    if (t == 0) return;
    float qq = 0.f, kk = 0.f, qk = 0.f;
    #pragma unroll
    for (int c = 0; c < NCHUNK; ++c) {
        size_t p = ((size_t)c * Bc * Lc + idx) * 3;
        qq += partial[p];
        kk += partial[p + 1];
        qk += partial[p + 2];
    }
    float T = expf(ltemp[0]);
    T = fminf(fmaxf(T, 0.1f), 10.0f);
    float den = fmaxf(sqrtf(qq), 1e-12f) * fmaxf(sqrtf(kk), 1e-12f);
    bl_out[idx] = (1.0f - qk / den) * T + bbias[0];
}

// ---------------- Kernel 2: boundary decision + stable compaction ----------------
__global__ __launch_bounds__(256) void k2_boundary(
    const float* __restrict__ bl_in, const int* __restrict__ mask,
    float* __restrict__ pv, int* __restrict__ bpos, int* __restrict__ nb)
{
    int b = blockIdx.x;
    int tid = threadIdx.x;
    const float* blb = bl_in + b * Lc;
    const int* mb = mask + b * Lc;

    float blv[8]; int f[8];
    int t0 = tid * 8;
    int s = 0;
    #pragma unroll
    for (int i = 0; i < 8; ++i) {
        int t = t0 + i;
        float v = (t == 0) ? 10.0f : blb[t];
        blv[i] = v;
        f[i] = (v > 0.0f && mb[t] != 0) ? 1 : 0;
        s += f[i];
    }
    int lane = tid & 63, wv = tid >> 6;
    int sc = s;
    #pragma unroll
    for (int off = 1; off < 64; off <<= 1) {
        int o = __shfl_up(sc, off, 64);
        if (lane >= off) sc += o;
    }
    __shared__ int wsums[4];
    if (lane == 63) wsums[wv] = sc;
    __syncthreads();
    int woff = 0;
    #pragma unroll
    for (int w = 0; w < 4; ++w) woff += (w < wv) ? wsums[w] : 0;
    int excl = woff + sc - s;
    int total = wsums[0] + wsums[1] + wsums[2] + wsums[3];

    float* pvb = pv + b * STRIDE;
    int* bpb = bpos + b * STRIDE;
    int r = excl;
    #pragma unroll
    for (int i = 0; i < 8; ++i) {
        if (f[i]) {
            int t = t0 + i;
            float p;
            if (t == 0) {
                p = 1.0f;
            } else {
                p = 1.0f / (1.0f + expf(-2.0f * blv[i]));
                p = fminf(fmaxf(p, 1e-4f), 1.0f - 1e-4f);
            }
            bpb[r] = t;
            pvb[r] = p;
            r += 1;
        }
    }
    if (tid == 0) nb[b] = total;
    for (int j = total + tid; j < STRIDE; j += 256) { bpb[j] = Lc; pvb[j] = 0.0f; }
}

// ---------------- Kernel 3: EMA over boundary tokens + span expansion ----------------
__global__ __launch_bounds__(128) void k3_ema(
    const float* __restrict__ H, const float* __restrict__ pv,
    const int* __restrict__ bpos, const int* __restrict__ nb,
    float* __restrict__ out)
{
    int b = blockIdx.x;
    int ch = blockIdx.y * 128 + threadIdx.x;
    const float* Hb = H + (size_t)b * Lc * Dc + ch;
    float* Ob = out + (size_t)b * Lc * Dc + ch;
    const float* pvb = pv + b * STRIDE;
    const int* bpb = bpos + b * STRIDE;
    int n = nb[b];
    int ng = (n + G - 1) / G;

    float xA[G], pA[G]; int tA[G + 1];
    #pragma unroll
    for (int i = 0; i < G; ++i) {
        int t = bpb[i];
        tA[i] = t;
        pA[i] = pvb[i];
        xA[i] = (t < Lc) ? Hb[(size_t)t * Dc] : 0.0f;
    }
    tA[G] = bpb[G];

    float h = 0.0f;
    for (int g = 0; g < ng; ++g) {
        int nbase = (g + 1) * G;
        float xB[G], pB[G]; int tB[G + 1];
        #pragma unroll
        for (int i = 0; i < G; ++i) {
            int t = bpb[nbase + i];
            tB[i] = t;
            pB[i] = pvb[nbase + i];
            xB[i] = (t < Lc) ? Hb[(size_t)t * Dc] : 0.0f;
        }
        tB[G] = bpb[nbase + G];
        #pragma unroll
        for (int i = 0; i < G; ++i) {
            h = (1.0f - pA[i]) * h + pA[i] * xA[i];
            int te = tA[i + 1];
            for (int tt = tA[i]; tt < te; ++tt) Ob[(size_t)tt * Dc] = h;
        }
        #pragma unroll
        for (int i = 0; i < G; ++i) { xA[i] = xB[i]; pA[i] = pB[i]; tA[i] = tB[i]; }
        tA[G] = tB[G];
    }
}

extern "C" void kernel_launch(void* const* d_in, const int* in_sizes, int n_in,
                              void* d_out, int out_size, void* d_ws, size_t ws_size,
                              hipStream_t stream)
{
    const float* H  = (const float*)d_in[0];
    const float* Wq = (const float*)d_in[1];
    const float* Wk = (const float*)d_in[2];
    const float* lt = (const float*)d_in[3];
    const float* bb = (const float*)d_in[4];
    const int* mask = (const int*)d_in[5];
    float* out = (float*)d_out;

    char* ws = (char*)d_ws;
    float* bl   = (float*)ws;                                     // 8*2048 floats
    float* pv   = (float*)(ws + (size_t)Bc * Lc * 4);
    int*   bpos = (int*)  (ws + (size_t)Bc * Lc * 4 + (size_t)Bc * STRIDE * 4);
    int*   nbp  = (int*)  (ws + (size_t)Bc * Lc * 4 + 2ull * Bc * STRIDE * 4);
    // chunk partials (18 x 16384 x 3 fp32 = 3.5 MB) live in d_out's head;
    // K3 fully overwrites d_out afterwards.
    float* partial = out;

    hipLaunchKernelGGL(k1_gemm, dim3(Bc * 16, NCHUNK), dim3(256), 0, stream,
                       H, Wq, Wk, partial);
    hipLaunchKernelGGL(k1b_reduce, dim3((Bc * Lc + 255) / 256), dim3(256), 0, stream,
                       partial, lt, bb, bl);
    hipLaunchKernelGGL(k2_boundary, dim3(Bc), dim3(256), 0, stream,
                       bl, mask, pv, bpos, nbp);
    hipLaunchKernelGGL(k3_ema, dim3(Bc, 9), dim3(128), 0, stream,
                       H, pv, bpos, nbp, out);
}

// Round 9
// 436.365 us; speedup vs baseline: 57.1787x; 3.0599x over previous
//
#include <hip/hip_runtime.h>
#include <hip/hip_bf16.h>
#include <cstdint>
#include <cstddef>

#define Bc 8
#define Lc 2048
#define Dc 1152
#define STRIDE 2080
#define G 8
#define NCHUNK 36            // e-chunks of 32

// ---- workspace layout (bytes) ----
#define WCV_OFF   0u                 // 2304*36*128 = 10,616,832
#define PART_OFF  10616832u          // 36*16384*3*4 = 7,077,888
#define BL_OFF    17694720u          // 8*2048*4
#define PV_OFF    17760256u          // 8*2080*4
#define BPOS_OFF  17826816u          // 8*2080*4
#define NB_OFF    17893376u

using bf16x8 = __attribute__((ext_vector_type(8))) short;
using f32x4  = __attribute__((ext_vector_type(4))) float;
#define MFMA(a, b, c) __builtin_amdgcn_mfma_f32_16x16x32_bf16(a, b, c, 0, 0, 0)

__device__ __forceinline__ void gld16(const void* g, void* l) {
    __builtin_amdgcn_global_load_lds(
        (const __attribute__((address_space(1))) void*)(g),
        (__attribute__((address_space(3))) void*)(l), 16, 0, 0);
}

__device__ __forceinline__ unsigned short bf_hi(float x) {
    __hip_bfloat16 h = __float2bfloat16(x);
    return *reinterpret_cast<unsigned short*>(&h);
}
__device__ __forceinline__ float bf_f(unsigned short u) {
    __hip_bfloat16 h; *reinterpret_cast<unsigned short*>(&h) = u;
    return __bfloat162float(h);
}

// ---------------- Kernel 0: fp32 -> bf16 hi/lo split, staged layout ----------------
// Hcv (in d_out, 75.5 MB): per (row, ks): 128 B = [hi: 4x16B chunks][lo: 4x16B],
// chunk c holds k = ks*32 + 8c .. +7, LINEAR (swizzle applied at staging time).
// Wcv (in ws): same layout, rows = [Wq e 0..1151][Wk e 0..1151].
__global__ __launch_bounds__(256) void k0_convert(
    const float* __restrict__ H, const float* __restrict__ Wq,
    const float* __restrict__ Wk, char* __restrict__ Hcv, char* __restrict__ Wcv)
{
    int idx = blockIdx.x * 256 + threadIdx.x;
    if (idx >= (16384 + 2304) * 144) return;
    int cchunk = idx & 3;
    int ks = (idx >> 2) % 36;
    int row = idx / 144;
    const float* src;
    char* dst;
    if (row < 16384) {
        src = H + (size_t)row * Dc;
        dst = Hcv + ((size_t)row * 36 + ks) * 128;
    } else {
        int e = row - 16384;
        src = (e < Dc) ? (Wq + (size_t)e * Dc) : (Wk + (size_t)(e - Dc) * Dc);
        dst = Wcv + ((size_t)e * 36 + ks) * 128;
    }
    const float* s = src + ks * 32 + cchunk * 8;
    unsigned int hw0 = 0, hw1 = 0, hw2 = 0, hw3 = 0;
    unsigned int lw0 = 0, lw1 = 0, lw2 = 0, lw3 = 0;
    #define CV(i, HW, LW, SH)                                                  \
    {                                                                          \
        float x = s[i];                                                        \
        unsigned short h = bf_hi(x);                                           \
        unsigned short lo = bf_hi(x - bf_f(h));                                \
        HW |= ((unsigned int)h) << (SH);                                       \
        LW |= ((unsigned int)lo) << (SH);                                      \
    }
    CV(0, hw0, lw0, 0) CV(1, hw0, lw0, 16) CV(2, hw1, lw1, 0) CV(3, hw1, lw1, 16)
    CV(4, hw2, lw2, 0) CV(5, hw2, lw2, 16) CV(6, hw3, lw3, 0) CV(7, hw3, lw3, 16)
    #undef CV
    uint4 hv; hv.x = hw0; hv.y = hw1; hv.z = hw2; hv.w = hw3;
    uint4 lv; lv.x = lw0; lv.y = lw1; lv.z = lw2; lv.w = lw3;
    *(uint4*)(dst + cchunk * 16) = hv;
    *(uint4*)(dst + 64 + cchunk * 16) = lv;
}

// ---------------- Kernel 1: 3-product bf16-split MFMA GEMM + fused stats ----------------
// Block: 128 t-rows (window rows t0-1 .. t0+127 staged, 129 rows) x 32 e's
// (both Wq and Wk). Wave w: rowtiles {2w, 2w+1}. q-accs use H rows +0 (A-read),
// k-accs use H rows +1 (B-read, shifted inside the 129-row staged window).
// LDS tile rows are 128 B = [hi 4 chunks][lo 4 chunks], chunk slot s holds
// logical chunk s ^ ((row>>1)&3) (bank-uniform for the fragment read pattern:
// lane l reads row l&15, chunk l>>4). Fragment reads: base + imm offsets.
// MFMA C/D: col = lane&15 (e), row = (lane>>4)*4 + reg (t) [HW-verified].
// 3-product split: C = HhiWhi + HhiWlo + HloWhi (per-entry rel err ~2^-20).
__global__ __launch_bounds__(256, 2) void k1_mfma(
    const char* __restrict__ Hcv, const char* __restrict__ Wcv,
    float* __restrict__ partial)
{
    __shared__ __align__(16) char LdsB[24704];   // H 129*128=16512 | W 64*128=8192
    const int tid = threadIdx.x;
    const int bx = blockIdx.x;          // batch*16 + mtile
    const int j = blockIdx.y;           // e-chunk 0..35
    const int batch = bx >> 4;
    const int mt = bx & 15;
    const int t0 = 1 + mt * 128;
    const int rowbase = batch * Lc + t0 - 1;
    const int rowmax = batch * Lc + (Lc - 1);

    const int l = tid & 63;
    const int w = tid >> 6;
    const int rl = l & 15;
    const int c = l >> 4;

    const int offA = rl * 128 + ((c ^ ((rl >> 1) & 3)) << 4);
    const int offB = (rl + 1) * 128 + ((c ^ (((rl + 1) >> 1) & 3)) << 4);
    const char* Hb = LdsB;
    const char* Wb = LdsB + 16512;

    f32x4 q00 = {0.f,0.f,0.f,0.f}, q01 = {0.f,0.f,0.f,0.f};
    f32x4 q10 = {0.f,0.f,0.f,0.f}, q11 = {0.f,0.f,0.f,0.f};
    f32x4 k00 = {0.f,0.f,0.f,0.f}, k01 = {0.f,0.f,0.f,0.f};
    f32x4 k10 = {0.f,0.f,0.f,0.f}, k11 = {0.f,0.f,0.f,0.f};

    for (int ks = 0; ks < 36; ++ks) {
        // stage H window: 1032 16B units; LDS dest linear, source chunk swizzled
        for (int u = tid; u < 1032; u += 256) {
            int row = u >> 3;
            int p = (u >> 2) & 1;
            int ch = (u & 3) ^ ((row >> 1) & 3);
            int grow = rowbase + row; if (grow > rowmax) grow = rowmax;
            gld16(Hcv + ((size_t)grow * 36 + ks) * 128 + p * 64 + ch * 16,
                  LdsB + u * 16);
        }
        // stage W: rows 0-31 = Wq e 32j..+31, rows 32-63 = Wk e 32j..+31
        for (int u = tid; u < 512; u += 256) {
            int row = u >> 3;
            int p = (u >> 2) & 1;
            int ch = (u & 3) ^ ((row >> 1) & 3);
            int erow = (row < 32) ? (j * 32 + row) : (Dc + j * 32 + row - 32);
            gld16(Wcv + ((size_t)erow * 36 + ks) * 128 + p * 64 + ch * 16,
                  LdsB + 16512 + u * 16);
        }
        __syncthreads();

        bf16x8 wq0h = *(const bf16x8*)(Wb + offA);
        bf16x8 wq0l = *(const bf16x8*)(Wb + offA + 64);
        bf16x8 wq1h = *(const bf16x8*)(Wb + 2048 + offA);
        bf16x8 wq1l = *(const bf16x8*)(Wb + 2048 + offA + 64);
        bf16x8 wk0h = *(const bf16x8*)(Wb + 4096 + offA);
        bf16x8 wk0l = *(const bf16x8*)(Wb + 4096 + offA + 64);
        bf16x8 wk1h = *(const bf16x8*)(Wb + 6144 + offA);
        bf16x8 wk1l = *(const bf16x8*)(Wb + 6144 + offA + 64);
        {
            const char* hm = Hb + (2 * w) * 2048;
            bf16x8 ah = *(const bf16x8*)(hm + offA);
            bf16x8 al = *(const bf16x8*)(hm + offA + 64);
            bf16x8 bh = *(const bf16x8*)(hm + offB);
            bf16x8 bl = *(const bf16x8*)(hm + offB + 64);
            q00 = MFMA(ah, wq0h, q00); q00 = MFMA(ah, wq0l, q00); q00 = MFMA(al, wq0h, q00);
            q01 = MFMA(ah, wq1h, q01); q01 = MFMA(ah, wq1l, q01); q01 = MFMA(al, wq1h, q01);
            k00 = MFMA(bh, wk0h, k00); k00 = MFMA(bh, wk0l, k00); k00 = MFMA(bl, wk0h, k00);
            k01 = MFMA(bh, wk1h, k01); k01 = MFMA(bh, wk1l, k01); k01 = MFMA(bl, wk1h, k01);
        }
        {
            const char* hm = Hb + (2 * w + 1) * 2048;
            bf16x8 ah = *(const bf16x8*)(hm + offA);
            bf16x8 al = *(const bf16x8*)(hm + offA + 64);
            bf16x8 bh = *(const bf16x8*)(hm + offB);
            bf16x8 bl = *(const bf16x8*)(hm + offB + 64);
            q10 = MFMA(ah, wq0h, q10); q10 = MFMA(ah, wq0l, q10); q10 = MFMA(al, wq0h, q10);
            q11 = MFMA(ah, wq1h, q11); q11 = MFMA(ah, wq1l, q11); q11 = MFMA(al, wq1h, q11);
            k10 = MFMA(bh, wk0h, k10); k10 = MFMA(bh, wk0l, k10); k10 = MFMA(bl, wk0h, k10);
            k11 = MFMA(bh, wk1h, k11); k11 = MFMA(bh, wk1l, k11); k11 = MFMA(bl, wk1h, k11);
        }
        __syncthreads();
    }

    // stats: t-row = t0 + 16*(2w+m) + c*4 + v; q from A (H row t-1), k from
    // shifted B (H row t). e-reduce: 2 col-frags + 16-lane shuffle.
    #define EMIT(QA, QB, KA, KB, TROW)                                         \
    {                                                                          \
        float qq = (QA) * (QA) + (QB) * (QB);                                  \
        float kk = (KA) * (KA) + (KB) * (KB);                                  \
        float qk = (QA) * (KA) + (QB) * (KB);                                  \
        qq += __shfl_xor(qq, 1, 64); qq += __shfl_xor(qq, 2, 64);              \
        qq += __shfl_xor(qq, 4, 64); qq += __shfl_xor(qq, 8, 64);              \
        kk += __shfl_xor(kk, 1, 64); kk += __shfl_xor(kk, 2, 64);              \
        kk += __shfl_xor(kk, 4, 64); kk += __shfl_xor(kk, 8, 64);              \
        qk += __shfl_xor(qk, 1, 64); qk += __shfl_xor(qk, 2, 64);              \
        qk += __shfl_xor(qk, 4, 64); qk += __shfl_xor(qk, 8, 64);              \
        if (rl == 0) {                                                         \
            int t = t0 + (TROW);                                               \
            if (t < Lc) {                                                      \
                size_t pidx = (((size_t)j * Bc + batch) * Lc + t) * 3;         \
                partial[pidx] = qq; partial[pidx + 1] = kk;                    \
                partial[pidx + 2] = qk;                                        \
            }                                                                  \
        }                                                                      \
    }
    EMIT(q00[0], q01[0], k00[0], k01[0], 32 * w + c * 4 + 0)
    EMIT(q00[1], q01[1], k00[1], k01[1], 32 * w + c * 4 + 1)
    EMIT(q00[2], q01[2], k00[2], k01[2], 32 * w + c * 4 + 2)
    EMIT(q00[3], q01[3], k00[3], k01[3], 32 * w + c * 4 + 3)
    EMIT(q10[0], q11[0], k10[0], k11[0], 32 * w + 16 + c * 4 + 0)
    EMIT(q10[1], q11[1], k10[1], k11[1], 32 * w + 16 + c * 4 + 1)
    EMIT(q10[2], q11[2], k10[2], k11[2], 32 * w + 16 + c * 4 + 2)
    EMIT(q10[3], q11[3], k10[3], k11[3], 32 * w + 16 + c * 4 + 3)
    #undef EMIT
}

// ---------------- Kernel 1b: deterministic chunk-reduce -> bl ----------------
__global__ __launch_bounds__(256) void k1b_reduce(
    const float* __restrict__ partial, const float* __restrict__ ltemp,
    const float* __restrict__ bbias, float* __restrict__ bl_out)
{
    int idx = blockIdx.x * 256 + threadIdx.x;   // batch*Lc + t
    if (idx >= Bc * Lc) return;
    int t = idx & (Lc - 1);
    if (t == 0) return;
    float qq = 0.f, kk = 0.f, qk = 0.f;
    #pragma unroll
    for (int cn = 0; cn < NCHUNK; ++cn) {
        size_t p = ((size_t)cn * Bc * Lc + idx) * 3;
        qq += partial[p];
        kk += partial[p + 1];
        qk += partial[p + 2];
    }
    float T = expf(ltemp[0]);
    T = fminf(fmaxf(T, 0.1f), 10.0f);
    float den = fmaxf(sqrtf(qq), 1e-12f) * fmaxf(sqrtf(kk), 1e-12f);
    bl_out[idx] = (1.0f - qk / den) * T + bbias[0];
}

// ---------------- Kernel 2: boundary decision + stable compaction ----------------
__global__ __launch_bounds__(256) void k2_boundary(
    const float* __restrict__ bl_in, const int* __restrict__ mask,
    float* __restrict__ pv, int* __restrict__ bpos, int* __restrict__ nb)
{
    int b = blockIdx.x;
    int tid = threadIdx.x;
    const float* blb = bl_in + b * Lc;
    const int* mb = mask + b * Lc;

    float blv[8]; int f[8];
    int t0 = tid * 8;
    int s = 0;
    #pragma unroll
    for (int i = 0; i < 8; ++i) {
        int t = t0 + i;
        float v = (t == 0) ? 10.0f : blb[t];
        blv[i] = v;
        f[i] = (v > 0.0f && mb[t] != 0) ? 1 : 0;
        s += f[i];
    }
    int lane = tid & 63, wv = tid >> 6;
    int sc = s;
    #pragma unroll
    for (int off = 1; off < 64; off <<= 1) {
        int o = __shfl_up(sc, off, 64);
        if (lane >= off) sc += o;
    }
    __shared__ int wsums[4];
    if (lane == 63) wsums[wv] = sc;
    __syncthreads();
    int woff = 0;
    #pragma unroll
    for (int w2 = 0; w2 < 4; ++w2) woff += (w2 < wv) ? wsums[w2] : 0;
    int excl = woff + sc - s;
    int total = wsums[0] + wsums[1] + wsums[2] + wsums[3];

    float* pvb = pv + b * STRIDE;
    int* bpb = bpos + b * STRIDE;
    int r = excl;
    #pragma unroll
    for (int i = 0; i < 8; ++i) {
        if (f[i]) {
            int t = t0 + i;
            float p;
            if (t == 0) {
                p = 1.0f;
            } else {
                p = 1.0f / (1.0f + expf(-2.0f * blv[i]));
                p = fminf(fmaxf(p, 1e-4f), 1.0f - 1e-4f);
            }
            bpb[r] = t;
            pvb[r] = p;
            r += 1;
        }
    }
    if (tid == 0) nb[b] = total;
    for (int q = total + tid; q < STRIDE; q += 256) { bpb[q] = Lc; pvb[q] = 0.0f; }
}

// ---------------- Kernel 3: EMA over boundary tokens + span expansion ----------------
__global__ __launch_bounds__(128) void k3_ema(
    const float* __restrict__ H, const float* __restrict__ pv,
    const int* __restrict__ bpos, const int* __restrict__ nb,
    float* __restrict__ out)
{
    int b = blockIdx.x;
    int ch = blockIdx.y * 128 + threadIdx.x;
    const float* Hb = H + (size_t)b * Lc * Dc + ch;
    float* Ob = out + (size_t)b * Lc * Dc + ch;
    const float* pvb = pv + b * STRIDE;
    const int* bpb = bpos + b * STRIDE;
    int n = nb[b];
    int ng = (n + G - 1) / G;

    float xA[G], pA[G]; int tA[G + 1];
    #pragma unroll
    for (int i = 0; i < G; ++i) {
        int t = bpb[i];
        tA[i] = t;
        pA[i] = pvb[i];
        xA[i] = (t < Lc) ? Hb[(size_t)t * Dc] : 0.0f;
    }
    tA[G] = bpb[G];

    float h = 0.0f;
    for (int g = 0; g < ng; ++g) {
        int nbase = (g + 1) * G;
        float xB[G], pB[G]; int tB[G + 1];
        #pragma unroll
        for (int i = 0; i < G; ++i) {
            int t = bpb[nbase + i];
            tB[i] = t;
            pB[i] = pvb[nbase + i];
            xB[i] = (t < Lc) ? Hb[(size_t)t * Dc] : 0.0f;
        }
        tB[G] = bpb[nbase + G];
        #pragma unroll
        for (int i = 0; i < G; ++i) {
            h = (1.0f - pA[i]) * h + pA[i] * xA[i];
            int te = tA[i + 1];
            for (int tt = tA[i]; tt < te; ++tt) Ob[(size_t)tt * Dc] = h;
        }
        #pragma unroll
        for (int i = 0; i < G; ++i) { xA[i] = xB[i]; pA[i] = pB[i]; tA[i] = tB[i]; }
        tA[G] = tB[G];
    }
}

extern "C" void kernel_launch(void* const* d_in, const int* in_sizes, int n_in,
                              void* d_out, int out_size, void* d_ws, size_t ws_size,
                              hipStream_t stream)
{
    const float* H  = (const float*)d_in[0];
    const float* Wq = (const float*)d_in[1];
    const float* Wk = (const float*)d_in[2];
    const float* lt = (const float*)d_in[3];
    const float* bb = (const float*)d_in[4];
    const int* mask = (const int*)d_in[5];
    float* out = (float*)d_out;

    char* ws = (char*)d_ws;
    char*  Hcv  = (char*)d_out;                  // 75.5 MB, exactly fills d_out;
                                                 // K3 overwrites it at the end.
    char*  Wcv  = ws + WCV_OFF;                  // 10.6 MB
    float* part = (float*)(ws + PART_OFF);       // 7.1 MB
    float* bl   = (float*)(ws + BL_OFF);
    float* pv   = (float*)(ws + PV_OFF);
    int*   bpos = (int*)(ws + BPOS_OFF);
    int*   nbp  = (int*)(ws + NB_OFF);

    hipLaunchKernelGGL(k0_convert, dim3(((16384 + 2304) * 144 + 255) / 256),
                       dim3(256), 0, stream, H, Wq, Wk, Hcv, Wcv);
    hipLaunchKernelGGL(k1_mfma, dim3(Bc * 16, NCHUNK), dim3(256), 0, stream,
                       Hcv, Wcv, part);
    hipLaunchKernelGGL(k1b_reduce, dim3((Bc * Lc + 255) / 256), dim3(256), 0, stream,
                       part, lt, bb, bl);
    hipLaunchKernelGGL(k2_boundary, dim3(Bc), dim3(256), 0, stream,
                       bl, mask, pv, bpos, nbp);
    hipLaunchKernelGGL(k3_ema, dim3(Bc, 9), dim3(128), 0, stream,
                       H, pv, bpos, nbp, out);
}

// Round 10
// 404.896 us; speedup vs baseline: 61.6227x; 1.0777x over previous
//
#include <hip/hip_runtime.h>
#include <hip/hip_bf16.h>
#include <cstdint>
#include <cstddef>

#define Bc 8
#define Lc 2048
#define Dc 1152
#define STRIDE 2080
#define G 8
#define NCHUNK 36            // e-chunks of 32

// ---- workspace layout (bytes) ----
#define WCV_OFF   0u                 // 2304*36*128 = 10,616,832
#define PART_OFF  10616832u          // 36*16384*3*4 = 7,077,888
#define BL_OFF    17694720u          // 8*2048*4
#define PV_OFF    17760256u          // 8*2080*4
#define BPOS_OFF  17826816u          // 8*2080*4
#define NB_OFF    17893376u

using bf16x8 = __attribute__((ext_vector_type(8))) short;
using f32x4  = __attribute__((ext_vector_type(4))) float;
#define MFMA(a, b, c) __builtin_amdgcn_mfma_f32_16x16x32_bf16(a, b, c, 0, 0, 0)

__device__ __forceinline__ void gld16(const void* g, void* l) {
    __builtin_amdgcn_global_load_lds(
        (const __attribute__((address_space(1))) void*)(g),
        (__attribute__((address_space(3))) void*)(l), 16, 0, 0);
}

__device__ __forceinline__ unsigned short bf_hi(float x) {
    __hip_bfloat16 h = __float2bfloat16(x);
    return *reinterpret_cast<unsigned short*>(&h);
}
__device__ __forceinline__ float bf_f(unsigned short u) {
    __hip_bfloat16 h; *reinterpret_cast<unsigned short*>(&h) = u;
    return __bfloat162float(h);
}

// ---------------- Kernel 0: fp32 -> bf16 hi/lo split, staged layout ----------------
// Hcv (in d_out, 75.5 MB): per (row, ks): 128 B = [hi: 4x16B chunks][lo: 4x16B],
// chunk c holds k = ks*32 + 8c .. +7, LINEAR (swizzle applied at staging time).
// Wcv (in ws): same layout, rows = [Wq e 0..1151][Wk e 0..1151].
__global__ __launch_bounds__(256) void k0_convert(
    const float* __restrict__ H, const float* __restrict__ Wq,
    const float* __restrict__ Wk, char* __restrict__ Hcv, char* __restrict__ Wcv)
{
    int idx = blockIdx.x * 256 + threadIdx.x;
    if (idx >= (16384 + 2304) * 144) return;
    int cchunk = idx & 3;
    int ks = (idx >> 2) % 36;
    int row = idx / 144;
    const float* src;
    char* dst;
    if (row < 16384) {
        src = H + (size_t)row * Dc;
        dst = Hcv + ((size_t)row * 36 + ks) * 128;
    } else {
        int e = row - 16384;
        src = (e < Dc) ? (Wq + (size_t)e * Dc) : (Wk + (size_t)(e - Dc) * Dc);
        dst = Wcv + ((size_t)e * 36 + ks) * 128;
    }
    const float* s = src + ks * 32 + cchunk * 8;
    unsigned int hw0 = 0, hw1 = 0, hw2 = 0, hw3 = 0;
    unsigned int lw0 = 0, lw1 = 0, lw2 = 0, lw3 = 0;
    #define CV(i, HW, LW, SH)                                                  \
    {                                                                          \
        float x = s[i];                                                        \
        unsigned short h = bf_hi(x);                                           \
        unsigned short lo = bf_hi(x - bf_f(h));                                \
        HW |= ((unsigned int)h) << (SH);                                       \
        LW |= ((unsigned int)lo) << (SH);                                      \
    }
    CV(0, hw0, lw0, 0) CV(1, hw0, lw0, 16) CV(2, hw1, lw1, 0) CV(3, hw1, lw1, 16)
    CV(4, hw2, lw2, 0) CV(5, hw2, lw2, 16) CV(6, hw3, lw3, 0) CV(7, hw3, lw3, 16)
    #undef CV
    uint4 hv; hv.x = hw0; hv.y = hw1; hv.z = hw2; hv.w = hw3;
    uint4 lv; lv.x = lw0; lv.y = lw1; lv.z = lw2; lv.w = lw3;
    *(uint4*)(dst + cchunk * 16) = hv;
    *(uint4*)(dst + 64 + cchunk * 16) = lv;
}

// ---------------- Kernel 1: 3-product bf16-split MFMA GEMM + fused stats ----------------
// Identical math/mapping to the verified round-9 kernel; three changes:
//  * FULL 8-slot XOR swizzle: LDS slot s of row r holds source chunk s^(r&7)
//    (chunks 0-3 = hi, 4-7 = lo). Frag read of chunk c from 16 rows spreads
//    over 8 slots -> 2 lanes/bank (free), vs the old 2-bit swizzle's 4-way.
//  * Grid (j fast, tile slow): consecutive blocks stage the SAME H tile ->
//    L2-resident (old order re-fetched Hcv from HBM 36x, FETCH 590 MB).
//  * Staging pointers hoisted out of the ks-loop (+= 128 per step).
// MFMA C/D: col = lane&15 (e), row = (lane>>4)*4 + reg (t) [verified r9].
__global__ __launch_bounds__(256, 2) void k1_mfma(
    const char* __restrict__ Hcv, const char* __restrict__ Wcv,
    float* __restrict__ partial)
{
    __shared__ __align__(16) char LdsB[24704];   // H 129*128=16512 | W 64*128=8192
    const int tid = threadIdx.x;
    const int j = blockIdx.x;           // e-chunk 0..35 (fast dim)
    const int bx = blockIdx.y;          // batch*16 + mtile
    const int batch = bx >> 4;
    const int mt = bx & 15;
    const int t0 = 1 + mt * 128;
    const int rowbase = batch * Lc + t0 - 1;
    const int rowmax = batch * Lc + (Lc - 1);

    // hoisted staging source pointers; each advances 128 B per ks
    const char *hp0, *hp1, *hp2, *hp3, *hpt, *wp0, *wp1;
    {
        #define HP(P, U)                                                       \
        {                                                                      \
            int u = (U); int row = u >> 3;                                     \
            int ch = (u & 7) ^ (row & 7);                                      \
            int grow = rowbase + row; if (grow > rowmax) grow = rowmax;        \
            P = Hcv + (size_t)grow * 4608 + (ch << 4);                         \
        }
        HP(hp0, tid) HP(hp1, tid + 256) HP(hp2, tid + 512) HP(hp3, tid + 768)
        HP(hpt, 1024 + (tid & 7))
        #undef HP
        #define WP(P, U)                                                       \
        {                                                                      \
            int u = (U); int row = u >> 3;                                     \
            int ch = (u & 7) ^ (row & 7);                                      \
            int erow = (row < 32) ? (j * 32 + row) : (Dc + j * 32 + row - 32); \
            P = Wcv + (size_t)erow * 4608 + (ch << 4);                         \
        }
        WP(wp0, tid) WP(wp1, tid + 256)
        #undef WP
    }

    const int l = tid & 63;
    const int w = tid >> 6;
    const int rl = l & 15;
    const int c = l >> 4;

    const int sA = c ^ (rl & 7);
    const int sB = c ^ ((rl + 1) & 7);      // (16rt+rl+1)&7 == (rl+1)&7 for all rl
    const int offAh = rl * 128 + (sA << 4);
    const int offAl = rl * 128 + ((sA ^ 4) << 4);
    const int offBh = (rl + 1) * 128 + (sB << 4);
    const int offBl = (rl + 1) * 128 + ((sB ^ 4) << 4);
    const char* Hb = LdsB;
    const char* Wb = LdsB + 16512;

    f32x4 q00 = {0.f,0.f,0.f,0.f}, q01 = {0.f,0.f,0.f,0.f};
    f32x4 q10 = {0.f,0.f,0.f,0.f}, q11 = {0.f,0.f,0.f,0.f};
    f32x4 k00 = {0.f,0.f,0.f,0.f}, k01 = {0.f,0.f,0.f,0.f};
    f32x4 k10 = {0.f,0.f,0.f,0.f}, k11 = {0.f,0.f,0.f,0.f};

    for (int ks = 0; ks < 36; ++ks) {
        gld16(hp0, LdsB + tid * 16);
        gld16(hp1, LdsB + (tid + 256) * 16);
        gld16(hp2, LdsB + (tid + 512) * 16);
        gld16(hp3, LdsB + (tid + 768) * 16);
        if (tid < 8) gld16(hpt, LdsB + (1024 + tid) * 16);
        gld16(wp0, LdsB + 16512 + tid * 16);
        gld16(wp1, LdsB + 16512 + (tid + 256) * 16);
        hp0 += 128; hp1 += 128; hp2 += 128; hp3 += 128; hpt += 128;
        wp0 += 128; wp1 += 128;
        __syncthreads();

        bf16x8 wq0h = *(const bf16x8*)(Wb + offAh);
        bf16x8 wq0l = *(const bf16x8*)(Wb + offAl);
        bf16x8 wq1h = *(const bf16x8*)(Wb + 2048 + offAh);
        bf16x8 wq1l = *(const bf16x8*)(Wb + 2048 + offAl);
        bf16x8 wk0h = *(const bf16x8*)(Wb + 4096 + offAh);
        bf16x8 wk0l = *(const bf16x8*)(Wb + 4096 + offAl);
        bf16x8 wk1h = *(const bf16x8*)(Wb + 6144 + offAh);
        bf16x8 wk1l = *(const bf16x8*)(Wb + 6144 + offAl);
        {
            const char* hm = Hb + (2 * w) * 2048;
            bf16x8 ah = *(const bf16x8*)(hm + offAh);
            bf16x8 al = *(const bf16x8*)(hm + offAl);
            bf16x8 bh = *(const bf16x8*)(hm + offBh);
            bf16x8 bl = *(const bf16x8*)(hm + offBl);
            q00 = MFMA(ah, wq0h, q00); q00 = MFMA(ah, wq0l, q00); q00 = MFMA(al, wq0h, q00);
            q01 = MFMA(ah, wq1h, q01); q01 = MFMA(ah, wq1l, q01); q01 = MFMA(al, wq1h, q01);
            k00 = MFMA(bh, wk0h, k00); k00 = MFMA(bh, wk0l, k00); k00 = MFMA(bl, wk0h, k00);
            k01 = MFMA(bh, wk1h, k01); k01 = MFMA(bh, wk1l, k01); k01 = MFMA(bl, wk1h, k01);
        }
        {
            const char* hm = Hb + (2 * w + 1) * 2048;
            bf16x8 ah = *(const bf16x8*)(hm + offAh);
            bf16x8 al = *(const bf16x8*)(hm + offAl);
            bf16x8 bh = *(const bf16x8*)(hm + offBh);
            bf16x8 bl = *(const bf16x8*)(hm + offBl);
            q10 = MFMA(ah, wq0h, q10); q10 = MFMA(ah, wq0l, q10); q10 = MFMA(al, wq0h, q10);
            q11 = MFMA(ah, wq1h, q11); q11 = MFMA(ah, wq1l, q11); q11 = MFMA(al, wq1h, q11);
            k10 = MFMA(bh, wk0h, k10); k10 = MFMA(bh, wk0l, k10); k10 = MFMA(bl, wk0h, k10);
            k11 = MFMA(bh, wk1h, k11); k11 = MFMA(bh, wk1l, k11); k11 = MFMA(bl, wk1h, k11);
        }
        __syncthreads();
    }

    // stats: t-row = t0 + 32w + c*4 + v (+16 for second rowtile)
    #define EMIT(QA, QB, KA, KB, TROW)                                         \
    {                                                                          \
        float qq = (QA) * (QA) + (QB) * (QB);                                  \
        float kk = (KA) * (KA) + (KB) * (KB);                                  \
        float qk = (QA) * (KA) + (QB) * (KB);                                  \
        qq += __shfl_xor(qq, 1, 64); qq += __shfl_xor(qq, 2, 64);              \
        qq += __shfl_xor(qq, 4, 64); qq += __shfl_xor(qq, 8, 64);              \
        kk += __shfl_xor(kk, 1, 64); kk += __shfl_xor(kk, 2, 64);              \
        kk += __shfl_xor(kk, 4, 64); kk += __shfl_xor(kk, 8, 64);              \
        qk += __shfl_xor(qk, 1, 64); qk += __shfl_xor(qk, 2, 64);              \
        qk += __shfl_xor(qk, 4, 64); qk += __shfl_xor(qk, 8, 64);              \
        if (rl == 0) {                                                         \
            int t = t0 + (TROW);                                               \
            if (t < Lc) {                                                      \
                size_t pidx = (((size_t)j * Bc + batch) * Lc + t) * 3;         \
                partial[pidx] = qq; partial[pidx + 1] = kk;                    \
                partial[pidx + 2] = qk;                                        \
            }                                                                  \
        }                                                                      \
    }
    EMIT(q00[0], q01[0], k00[0], k01[0], 32 * w + c * 4 + 0)
    EMIT(q00[1], q01[1], k00[1], k01[1], 32 * w + c * 4 + 1)
    EMIT(q00[2], q01[2], k00[2], k01[2], 32 * w + c * 4 + 2)
    EMIT(q00[3], q01[3], k00[3], k01[3], 32 * w + c * 4 + 3)
    EMIT(q10[0], q11[0], k10[0], k11[0], 32 * w + 16 + c * 4 + 0)
    EMIT(q10[1], q11[1], k10[1], k11[1], 32 * w + 16 + c * 4 + 1)
    EMIT(q10[2], q11[2], k10[2], k11[2], 32 * w + 16 + c * 4 + 2)
    EMIT(q10[3], q11[3], k10[3], k11[3], 32 * w + 16 + c * 4 + 3)
    #undef EMIT
}

// ---------------- Kernel 1b: deterministic chunk-reduce -> bl ----------------
__global__ __launch_bounds__(256) void k1b_reduce(
    const float* __restrict__ partial, const float* __restrict__ ltemp,
    const float* __restrict__ bbias, float* __restrict__ bl_out)
{
    int idx = blockIdx.x * 256 + threadIdx.x;   // batch*Lc + t
    if (idx >= Bc * Lc) return;
    int t = idx & (Lc - 1);
    if (t == 0) return;
    float qq = 0.f, kk = 0.f, qk = 0.f;
    #pragma unroll
    for (int cn = 0; cn < NCHUNK; ++cn) {
        size_t p = ((size_t)cn * Bc * Lc + idx) * 3;
        qq += partial[p];
        kk += partial[p + 1];
        qk += partial[p + 2];
    }
    float T = expf(ltemp[0]);
    T = fminf(fmaxf(T, 0.1f), 10.0f);
    float den = fmaxf(sqrtf(qq), 1e-12f) * fmaxf(sqrtf(kk), 1e-12f);
    bl_out[idx] = (1.0f - qk / den) * T + bbias[0];
}

// ---------------- Kernel 2: boundary decision + stable compaction ----------------
__global__ __launch_bounds__(256) void k2_boundary(
    const float* __restrict__ bl_in, const int* __restrict__ mask,
    float* __restrict__ pv, int* __restrict__ bpos, int* __restrict__ nb)
{
    int b = blockIdx.x;
    int tid = threadIdx.x;
    const float* blb = bl_in + b * Lc;
    const int* mb = mask + b * Lc;

    float blv[8]; int f[8];
    int t0 = tid * 8;
    int s = 0;
    #pragma unroll
    for (int i = 0; i < 8; ++i) {
        int t = t0 + i;
        float v = (t == 0) ? 10.0f : blb[t];
        blv[i] = v;
        f[i] = (v > 0.0f && mb[t] != 0) ? 1 : 0;
        s += f[i];
    }
    int lane = tid & 63, wv = tid >> 6;
    int sc = s;
    #pragma unroll
    for (int off = 1; off < 64; off <<= 1) {
        int o = __shfl_up(sc, off, 64);
        if (lane >= off) sc += o;
    }
    __shared__ int wsums[4];
    if (lane == 63) wsums[wv] = sc;
    __syncthreads();
    int woff = 0;
    #pragma unroll
    for (int w2 = 0; w2 < 4; ++w2) woff += (w2 < wv) ? wsums[w2] : 0;
    int excl = woff + sc - s;
    int total = wsums[0] + wsums[1] + wsums[2] + wsums[3];

    float* pvb = pv + b * STRIDE;
    int* bpb = bpos + b * STRIDE;
    int r = excl;
    #pragma unroll
    for (int i = 0; i < 8; ++i) {
        if (f[i]) {
            int t = t0 + i;
            float p;
            if (t == 0) {
                p = 1.0f;
            } else {
                p = 1.0f / (1.0f + expf(-2.0f * blv[i]));
                p = fminf(fmaxf(p, 1e-4f), 1.0f - 1e-4f);
            }
            bpb[r] = t;
            pvb[r] = p;
            r += 1;
        }
    }
    if (tid == 0) nb[b] = total;
    for (int q = total + tid; q < STRIDE; q += 256) { bpb[q] = Lc; pvb[q] = 0.0f; }
}

// ---------------- Kernel 3: EMA over boundary tokens + span expansion ----------------
__global__ __launch_bounds__(128) void k3_ema(
    const float* __restrict__ H, const float* __restrict__ pv,
    const int* __restrict__ bpos, const int* __restrict__ nb,
    float* __restrict__ out)
{
    int b = blockIdx.x;
    int ch = blockIdx.y * 128 + threadIdx.x;
    const float* Hb = H + (size_t)b * Lc * Dc + ch;
    float* Ob = out + (size_t)b * Lc * Dc + ch;
    const float* pvb = pv + b * STRIDE;
    const int* bpb = bpos + b * STRIDE;
    int n = nb[b];
    int ng = (n + G - 1) / G;

    float xA[G], pA[G]; int tA[G + 1];
    #pragma unroll
    for (int i = 0; i < G; ++i) {
        int t = bpb[i];
        tA[i] = t;
        pA[i] = pvb[i];
        xA[i] = (t < Lc) ? Hb[(size_t)t * Dc] : 0.0f;
    }
    tA[G] = bpb[G];

    float h = 0.0f;
    for (int g = 0; g < ng; ++g) {
        int nbase = (g + 1) * G;
        float xB[G], pB[G]; int tB[G + 1];
        #pragma unroll
        for (int i = 0; i < G; ++i) {
            int t = bpb[nbase + i];
            tB[i] = t;
            pB[i] = pvb[nbase + i];
            xB[i] = (t < Lc) ? Hb[(size_t)t * Dc] : 0.0f;
        }
        tB[G] = bpb[nbase + G];
        #pragma unroll
        for (int i = 0; i < G; ++i) {
            h = (1.0f - pA[i]) * h + pA[i] * xA[i];
            int te = tA[i + 1];
            for (int tt = tA[i]; tt < te; ++tt) Ob[(size_t)tt * Dc] = h;
        }
        #pragma unroll
        for (int i = 0; i < G; ++i) { xA[i] = xB[i]; pA[i] = pB[i]; tA[i] = tB[i]; }
        tA[G] = tB[G];
    }
}

extern "C" void kernel_launch(void* const* d_in, const int* in_sizes, int n_in,
                              void* d_out, int out_size, void* d_ws, size_t ws_size,
                              hipStream_t stream)
{
    const float* H  = (const float*)d_in[0];
    const float* Wq = (const float*)d_in[1];
    const float* Wk = (const float*)d_in[2];
    const float* lt = (const float*)d_in[3];
    const float* bb = (const float*)d_in[4];
    const int* mask = (const int*)d_in[5];
    float* out = (float*)d_out;

    char* ws = (char*)d_ws;
    char*  Hcv  = (char*)d_out;                  // 75.5 MB, exactly fills d_out;
                                                 // K3 overwrites it at the end.
    char*  Wcv  = ws + WCV_OFF;                  // 10.6 MB
    float* part = (float*)(ws + PART_OFF);       // 7.1 MB
    float* bl   = (float*)(ws + BL_OFF);
    float* pv   = (float*)(ws + PV_OFF);
    int*   bpos = (int*)(ws + BPOS_OFF);
    int*   nbp  = (int*)(ws + NB_OFF);

    hipLaunchKernelGGL(k0_convert, dim3(((16384 + 2304) * 144 + 255) / 256),
                       dim3(256), 0, stream, H, Wq, Wk, Hcv, Wcv);
    hipLaunchKernelGGL(k1_mfma, dim3(NCHUNK, Bc * 16), dim3(256), 0, stream,
                       Hcv, Wcv, part);
    hipLaunchKernelGGL(k1b_reduce, dim3((Bc * Lc + 255) / 256), dim3(256), 0, stream,
                       part, lt, bb, bl);
    hipLaunchKernelGGL(k2_boundary, dim3(Bc), dim3(256), 0, stream,
                       bl, mask, pv, bpos, nbp);
    hipLaunchKernelGGL(k3_ema, dim3(Bc, 9), dim3(128), 0, stream,
                       H, pv, bpos, nbp, out);
}

// Round 11
// 364.891 us; speedup vs baseline: 68.3788x; 1.1096x over previous
//
#include <hip/hip_runtime.h>
#include <hip/hip_bf16.h>
#include <cstdint>
#include <cstddef>

#define Bc 8
#define Lc 2048
#define Dc 1152
#define STRIDE 2080
#define G 8
#define NCHUNK 18            // e-chunks of 64

// ---- workspace layout (bytes) ----
#define WCV_OFF   0u                 // 2304*36*128 = 10,616,832
#define PART_OFF  10616832u          // 18*16384*3*4 = 3,538,944 (region reserves 7 MB)
#define BL_OFF    17694720u
#define PV_OFF    17760256u
#define BPOS_OFF  17826816u
#define NB_OFF    17893376u

using bf16x8 = __attribute__((ext_vector_type(8))) short;
using f32x4  = __attribute__((ext_vector_type(4))) float;
#define MFMA(a, b, c) __builtin_amdgcn_mfma_f32_16x16x32_bf16(a, b, c, 0, 0, 0)

__device__ __forceinline__ void gld16(const void* g, void* l) {
    __builtin_amdgcn_global_load_lds(
        (const __attribute__((address_space(1))) void*)(g),
        (__attribute__((address_space(3))) void*)(l), 16, 0, 0);
}

__device__ __forceinline__ unsigned short bf_hi(float x) {
    __hip_bfloat16 h = __float2bfloat16(x);
    return *reinterpret_cast<unsigned short*>(&h);
}
__device__ __forceinline__ float bf_f(unsigned short u) {
    __hip_bfloat16 h; *reinterpret_cast<unsigned short*>(&h) = u;
    return __bfloat162float(h);
}

// ---------------- Kernel 0: fp32 -> bf16 hi/lo split, staged layout ----------------
// Hcv (in d_out): per (row, ks): 128 B = [hi: 4x16B chunks][lo: 4x16B].
// Wcv (in ws): same layout, rows = [Wq e 0..1151][Wk e 0..1151].
__global__ __launch_bounds__(256) void k0_convert(
    const float* __restrict__ H, const float* __restrict__ Wq,
    const float* __restrict__ Wk, char* __restrict__ Hcv, char* __restrict__ Wcv)
{
    int idx = blockIdx.x * 256 + threadIdx.x;
    if (idx >= (16384 + 2304) * 144) return;
    int cchunk = idx & 3;
    int ks = (idx >> 2) % 36;
    int row = idx / 144;
    const float* src;
    char* dst;
    if (row < 16384) {
        src = H + (size_t)row * Dc;
        dst = Hcv + ((size_t)row * 36 + ks) * 128;
    } else {
        int e = row - 16384;
        src = (e < Dc) ? (Wq + (size_t)e * Dc) : (Wk + (size_t)(e - Dc) * Dc);
        dst = Wcv + ((size_t)e * 36 + ks) * 128;
    }
    const float* s = src + ks * 32 + cchunk * 8;
    unsigned int hw0 = 0, hw1 = 0, hw2 = 0, hw3 = 0;
    unsigned int lw0 = 0, lw1 = 0, lw2 = 0, lw3 = 0;
    #define CV(i, HW, LW, SH)                                                  \
    {                                                                          \
        float x = s[i];                                                        \
        unsigned short h = bf_hi(x);                                           \
        unsigned short lo = bf_hi(x - bf_f(h));                                \
        HW |= ((unsigned int)h) << (SH);                                       \
        LW |= ((unsigned int)lo) << (SH);                                      \
    }
    CV(0, hw0, lw0, 0) CV(1, hw0, lw0, 16) CV(2, hw1, lw1, 0) CV(3, hw1, lw1, 16)
    CV(4, hw2, lw2, 0) CV(5, hw2, lw2, 16) CV(6, hw3, lw3, 0) CV(7, hw3, lw3, 16)
    #undef CV
    uint4 hv; hv.x = hw0; hv.y = hw1; hv.z = hw2; hv.w = hw3;
    uint4 lv; lv.x = lw0; lv.y = lw1; lv.z = lw2; lv.w = lw3;
    *(uint4*)(dst + cchunk * 16) = hv;
    *(uint4*)(dst + 64 + cchunk * 16) = lv;
}

// ---------------- Kernel 1: 3-product bf16-split MFMA GEMM + fused stats ----------------
// vs round 10 (verified): e-width per block 32 -> 64 (4 e-frags/wave; reads per
// MFMA 0.667 -> 0.5 -- LDS-read-bound kernel), XCD-local bid remap (each XCD
// stages whole tile-groups from its own L2), staging pointers collapsed to 3
// (rows +32k share the swizzle since 32k = 0 mod 8 -> constant byte offsets).
// sched_barrier(0) pins each e-frag phase: max 16 W-frag regs live (128-VGPR
// wall, rounds 3/5/6/7: exceeding it = scratch spill = 10-20x slowdown).
__global__ __launch_bounds__(256, 2) void k1_mfma(
    const char* __restrict__ Hcv, const char* __restrict__ Wcv,
    float* __restrict__ partial)
{
    __shared__ __align__(16) char LdsB[32896];   // H 129*128=16512 | W 128*128=16384
    const int tid = threadIdx.x;
    const int bid = blockIdx.x;
    const int x = bid & 7;               // XCD (round-robin dispatch heuristic)
    const int r = bid >> 3;              // 0..287
    const int g = x + 8 * (r / 18);      // tile-group 0..127 (16 per XCD)
    const int j = r % 18;                // e-chunk 0..17
    const int batch = g >> 4;
    const int mt = g & 15;
    const int t0 = 1 + mt * 128;
    const int rowbase = batch * Lc + t0 - 1;
    const int rowmax = batch * Lc + (Lc - 1);

    // staging pointers (advance 128 B per ks). Derived rows +32k: same swizzle.
    const char *hp0, *hpt, *wp0;
    {
        int row = tid >> 3;                       // 0..31
        int ch = (tid & 7) ^ (row & 7);
        hp0 = Hcv + (size_t)(rowbase + row) * 4608 + (ch << 4);   // rows 0..127: no clamp needed
        int gr2 = rowbase + 128; if (gr2 > rowmax) gr2 = rowmax;  // tail row 128 may clamp
        hpt = Hcv + (size_t)gr2 * 4608 + ((tid & 7) << 4);
        wp0 = Wcv + (size_t)(j * 64 + row) * 4608 + (ch << 4);
    }

    const int l = tid & 63;
    const int w = tid >> 6;
    const int rl = l & 15;
    const int c = l >> 4;

    const int sA = c ^ (rl & 7);
    const int sB = c ^ ((rl + 1) & 7);
    const int offAh = rl * 128 + (sA << 4);
    const int offAl = rl * 128 + ((sA ^ 4) << 4);
    const int offBh = (rl + 1) * 128 + (sB << 4);
    const int offBl = (rl + 1) * 128 + ((sB ^ 4) << 4);
    const char* Wb = LdsB + 16512;

    f32x4 q00{0,0,0,0}, q01{0,0,0,0}, q02{0,0,0,0}, q03{0,0,0,0};
    f32x4 q10{0,0,0,0}, q11{0,0,0,0}, q12{0,0,0,0}, q13{0,0,0,0};
    f32x4 k00{0,0,0,0}, k01{0,0,0,0}, k02{0,0,0,0}, k03{0,0,0,0};
    f32x4 k10{0,0,0,0}, k11{0,0,0,0}, k12{0,0,0,0}, k13{0,0,0,0};

    for (int ks = 0; ks < 36; ++ks) {
        // H: 1032 16B units (129 rows); W: 1024 units (Wq rows 0-63, Wk 64-127;
        // Wk region = +1088 rows = +5013504 B beyond the row+64 arithmetic).
        gld16(hp0,           LdsB + tid * 16);
        gld16(hp0 + 147456,  LdsB + (tid + 256) * 16);
        gld16(hp0 + 294912,  LdsB + (tid + 512) * 16);
        gld16(hp0 + 442368,  LdsB + (tid + 768) * 16);
        if (tid < 8) gld16(hpt, LdsB + (1024 + tid) * 16);
        gld16(wp0,           LdsB + 16512 + tid * 16);
        gld16(wp0 + 147456,  LdsB + 16512 + (tid + 256) * 16);
        gld16(wp0 + 5308416, LdsB + 16512 + (tid + 512) * 16);
        gld16(wp0 + 5455872, LdsB + 16512 + (tid + 768) * 16);
        hp0 += 128; hpt += 128; wp0 += 128;
        __syncthreads();

        const char* hm0 = LdsB + (2 * w) * 2048;
        const char* hm1 = LdsB + (2 * w + 1) * 2048;
        bf16x8 a0h = *(const bf16x8*)(hm0 + offAh);
        bf16x8 a0l = *(const bf16x8*)(hm0 + offAl);
        bf16x8 b0h = *(const bf16x8*)(hm0 + offBh);
        bf16x8 b0l = *(const bf16x8*)(hm0 + offBl);
        bf16x8 a1h = *(const bf16x8*)(hm1 + offAh);
        bf16x8 a1l = *(const bf16x8*)(hm1 + offAl);
        bf16x8 b1h = *(const bf16x8*)(hm1 + offBh);
        bf16x8 b1l = *(const bf16x8*)(hm1 + offBl);

        #define FSTEP(f, QA0, QA1, KA0, KA1)                                   \
        {                                                                      \
            const char* wqb = Wb + (f) * 2048;                                 \
            bf16x8 wh = *(const bf16x8*)(wqb + offAh);                         \
            bf16x8 wl = *(const bf16x8*)(wqb + offAl);                         \
            QA0 = MFMA(a0h, wh, QA0); QA0 = MFMA(a0h, wl, QA0);                \
            QA0 = MFMA(a0l, wh, QA0);                                          \
            QA1 = MFMA(a1h, wh, QA1); QA1 = MFMA(a1h, wl, QA1);                \
            QA1 = MFMA(a1l, wh, QA1);                                          \
            const char* wkb = Wb + 8192 + (f) * 2048;                          \
            bf16x8 vh = *(const bf16x8*)(wkb + offAh);                         \
            bf16x8 vl = *(const bf16x8*)(wkb + offAl);                         \
            KA0 = MFMA(b0h, vh, KA0); KA0 = MFMA(b0h, vl, KA0);                \
            KA0 = MFMA(b0l, vh, KA0);                                          \
            KA1 = MFMA(b1h, vh, KA1); KA1 = MFMA(b1h, vl, KA1);                \
            KA1 = MFMA(b1l, vh, KA1);                                          \
            __builtin_amdgcn_sched_barrier(0);                                 \
        }
        FSTEP(0, q00, q10, k00, k10)
        FSTEP(1, q01, q11, k01, k11)
        FSTEP(2, q02, q12, k02, k12)
        FSTEP(3, q03, q13, k03, k13)
        #undef FSTEP
        __syncthreads();
    }

    // stats: t = t0 + 32w + 16m + c*4 + v; e-reduce over 4 frags + 16 lanes
    #define EMIT(QA, QB, QC, QD, KA, KB, KC, KD, TROW)                         \
    {                                                                          \
        float qq = (QA)*(QA) + (QB)*(QB) + (QC)*(QC) + (QD)*(QD);              \
        float kk = (KA)*(KA) + (KB)*(KB) + (KC)*(KC) + (KD)*(KD);              \
        float qk = (QA)*(KA) + (QB)*(KB) + (QC)*(KC) + (QD)*(KD);              \
        qq += __shfl_xor(qq, 1, 64); qq += __shfl_xor(qq, 2, 64);              \
        qq += __shfl_xor(qq, 4, 64); qq += __shfl_xor(qq, 8, 64);              \
        kk += __shfl_xor(kk, 1, 64); kk += __shfl_xor(kk, 2, 64);              \
        kk += __shfl_xor(kk, 4, 64); kk += __shfl_xor(kk, 8, 64);              \
        qk += __shfl_xor(qk, 1, 64); qk += __shfl_xor(qk, 2, 64);              \
        qk += __shfl_xor(qk, 4, 64); qk += __shfl_xor(qk, 8, 64);              \
        if (rl == 0) {                                                         \
            int t = t0 + (TROW);                                               \
            if (t < Lc) {                                                      \
                size_t pidx = (((size_t)j * Bc + batch) * Lc + t) * 3;         \
                partial[pidx] = qq; partial[pidx + 1] = kk;                    \
                partial[pidx + 2] = qk;                                        \
            }                                                                  \
        }                                                                      \
    }
    EMIT(q00[0], q01[0], q02[0], q03[0], k00[0], k01[0], k02[0], k03[0], 32*w + c*4 + 0)
    EMIT(q00[1], q01[1], q02[1], q03[1], k00[1], k01[1], k02[1], k03[1], 32*w + c*4 + 1)
    EMIT(q00[2], q01[2], q02[2], q03[2], k00[2], k01[2], k02[2], k03[2], 32*w + c*4 + 2)
    EMIT(q00[3], q01[3], q02[3], q03[3], k00[3], k01[3], k02[3], k03[3], 32*w + c*4 + 3)
    EMIT(q10[0], q11[0], q12[0], q13[0], k10[0], k11[0], k12[0], k13[0], 32*w + 16 + c*4 + 0)
    EMIT(q10[1], q11[1], q12[1], q13[1], k10[1], k11[1], k12[1], k13[1], 32*w + 16 + c*4 + 1)
    EMIT(q10[2], q11[2], q12[2], q13[2], k10[2], k11[2], k12[2], k13[2], 32*w + 16 + c*4 + 2)
    EMIT(q10[3], q11[3], q12[3], q13[3], k10[3], k11[3], k12[3], k13[3], 32*w + 16 + c*4 + 3)
    #undef EMIT
}

// ---------------- Kernel 1b: deterministic chunk-reduce -> bl ----------------
__global__ __launch_bounds__(256) void k1b_reduce(
    const float* __restrict__ partial, const float* __restrict__ ltemp,
    const float* __restrict__ bbias, float* __restrict__ bl_out)
{
    int idx = blockIdx.x * 256 + threadIdx.x;   // batch*Lc + t
    if (idx >= Bc * Lc) return;
    int t = idx & (Lc - 1);
    if (t == 0) return;
    float qq = 0.f, kk = 0.f, qk = 0.f;
    #pragma unroll
    for (int cn = 0; cn < NCHUNK; ++cn) {
        size_t p = ((size_t)cn * Bc * Lc + idx) * 3;
        qq += partial[p];
        kk += partial[p + 1];
        qk += partial[p + 2];
    }
    float T = expf(ltemp[0]);
    T = fminf(fmaxf(T, 0.1f), 10.0f);
    float den = fmaxf(sqrtf(qq), 1e-12f) * fmaxf(sqrtf(kk), 1e-12f);
    bl_out[idx] = (1.0f - qk / den) * T + bbias[0];
}

// ---------------- Kernel 2: boundary decision + stable compaction ----------------
__global__ __launch_bounds__(256) void k2_boundary(
    const float* __restrict__ bl_in, const int* __restrict__ mask,
    float* __restrict__ pv, int* __restrict__ bpos, int* __restrict__ nb)
{
    int b = blockIdx.x;
    int tid = threadIdx.x;
    const float* blb = bl_in + b * Lc;
    const int* mb = mask + b * Lc;

    float blv[8]; int f[8];
    int t0 = tid * 8;
    int s = 0;
    #pragma unroll
    for (int i = 0; i < 8; ++i) {
        int t = t0 + i;
        float v = (t == 0) ? 10.0f : blb[t];
        blv[i] = v;
        f[i] = (v > 0.0f && mb[t] != 0) ? 1 : 0;
        s += f[i];
    }
    int lane = tid & 63, wv = tid >> 6;
    int sc = s;
    #pragma unroll
    for (int off = 1; off < 64; off <<= 1) {
        int o = __shfl_up(sc, off, 64);
        if (lane >= off) sc += o;
    }
    __shared__ int wsums[4];
    if (lane == 63) wsums[wv] = sc;
    __syncthreads();
    int woff = 0;
    #pragma unroll
    for (int w2 = 0; w2 < 4; ++w2) woff += (w2 < wv) ? wsums[w2] : 0;
    int excl = woff + sc - s;
    int total = wsums[0] + wsums[1] + wsums[2] + wsums[3];

    float* pvb = pv + b * STRIDE;
    int* bpb = bpos + b * STRIDE;
    int r = excl;
    #pragma unroll
    for (int i = 0; i < 8; ++i) {
        if (f[i]) {
            int t = t0 + i;
            float p;
            if (t == 0) {
                p = 1.0f;
            } else {
                p = 1.0f / (1.0f + expf(-2.0f * blv[i]));
                p = fminf(fmaxf(p, 1e-4f), 1.0f - 1e-4f);
            }
            bpb[r] = t;
            pvb[r] = p;
            r += 1;
        }
    }
    if (tid == 0) nb[b] = total;
    for (int q = total + tid; q < STRIDE; q += 256) { bpb[q] = Lc; pvb[q] = 0.0f; }
}

// ---------------- Kernel 3: EMA over boundary tokens + span expansion ----------------
__global__ __launch_bounds__(128) void k3_ema(
    const float* __restrict__ H, const float* __restrict__ pv,
    const int* __restrict__ bpos, const int* __restrict__ nb,
    float* __restrict__ out)
{
    int b = blockIdx.x;
    int ch = blockIdx.y * 128 + threadIdx.x;
    const float* Hb = H + (size_t)b * Lc * Dc + ch;
    float* Ob = out + (size_t)b * Lc * Dc + ch;
    const float* pvb = pv + b * STRIDE;
    const int* bpb = bpos + b * STRIDE;
    int n = nb[b];
    int ng = (n + G - 1) / G;

    float xA[G], pA[G]; int tA[G + 1];
    #pragma unroll
    for (int i = 0; i < G; ++i) {
        int t = bpb[i];
        tA[i] = t;
        pA[i] = pvb[i];
        xA[i] = (t < Lc) ? Hb[(size_t)t * Dc] : 0.0f;
    }
    tA[G] = bpb[G];

    float h = 0.0f;
    for (int g = 0; g < ng; ++g) {
        int nbase = (g + 1) * G;
        float xB[G], pB[G]; int tB[G + 1];
        #pragma unroll
        for (int i = 0; i < G; ++i) {
            int t = bpb[nbase + i];
            tB[i] = t;
            pB[i] = pvb[nbase + i];
            xB[i] = (t < Lc) ? Hb[(size_t)t * Dc] : 0.0f;
        }
        tB[G] = bpb[nbase + G];
        #pragma unroll
        for (int i = 0; i < G; ++i) {
            h = (1.0f - pA[i]) * h + pA[i] * xA[i];
            int te = tA[i + 1];
            for (int tt = tA[i]; tt < te; ++tt) Ob[(size_t)tt * Dc] = h;
        }
        #pragma unroll
        for (int i = 0; i < G; ++i) { xA[i] = xB[i]; pA[i] = pB[i]; tA[i] = tB[i]; }
        tA[G] = tB[G];
    }
}

extern "C" void kernel_launch(void* const* d_in, const int* in_sizes, int n_in,
                              void* d_out, int out_size, void* d_ws, size_t ws_size,
                              hipStream_t stream)
{
    const float* H  = (const float*)d_in[0];
    const float* Wq = (const float*)d_in[1];
    const float* Wk = (const float*)d_in[2];
    const float* lt = (const float*)d_in[3];
    const float* bb = (const float*)d_in[4];
    const int* mask = (const int*)d_in[5];
    float* out = (float*)d_out;

    char* ws = (char*)d_ws;
    char*  Hcv  = (char*)d_out;                  // 75.5 MB staging in d_out;
                                                 // K3 overwrites it at the end.
    char*  Wcv  = ws + WCV_OFF;
    float* part = (float*)(ws + PART_OFF);
    float* bl   = (float*)(ws + BL_OFF);
    float* pv   = (float*)(ws + PV_OFF);
    int*   bpos = (int*)(ws + BPOS_OFF);
    int*   nbp  = (int*)(ws + NB_OFF);

    hipLaunchKernelGGL(k0_convert, dim3(((16384 + 2304) * 144 + 255) / 256),
                       dim3(256), 0, stream, H, Wq, Wk, Hcv, Wcv);
    hipLaunchKernelGGL(k1_mfma, dim3(NCHUNK * 128), dim3(256), 0, stream,
                       Hcv, Wcv, part);
    hipLaunchKernelGGL(k1b_reduce, dim3((Bc * Lc + 255) / 256), dim3(256), 0, stream,
                       part, lt, bb, bl);
    hipLaunchKernelGGL(k2_boundary, dim3(Bc), dim3(256), 0, stream,
                       bl, mask, pv, bpos, nbp);
    hipLaunchKernelGGL(k3_ema, dim3(Bc, 9), dim3(128), 0, stream,
                       H, pv, bpos, nbp, out);
}